// Round 1
// baseline (840.399 us; speedup 1.0000x reference)
//
#include <hip/hip_runtime.h>
#include <math.h>

// ---------------------------------------------------------------------------
// Generic tiled fp32 GEMM: out = A[M,K] @ W[K,N] + bias[N]
// Output row remap handles the k/v concat: global GEMM row m maps to output
// row (m/RPB)*OBS + out_off + (m%RPB).  (RPB=M, off=0 => identity.)
// Tile 64x64, 256 threads, 4x4 micro-tile per thread, K-tile 32.
// ---------------------------------------------------------------------------
#define TM 64
#define TN 64
#define KT 32

__global__ __launch_bounds__(256) void gemm_bias(
    const float* __restrict__ A, const float* __restrict__ W,
    const float* __restrict__ bias, float* __restrict__ out,
    int M, int K, int N, int RPB, int OBS, int out_off)
{
    __shared__ float As[KT][TM + 4];   // As[k][m]
    __shared__ float Bs[KT][TN + 4];   // Bs[k][n]

    const int t  = threadIdx.x;
    const int gn0 = blockIdx.x * TN;
    const int gm0 = blockIdx.y * TM;
    const int batch = gm0 / RPB;                       // block never straddles batches (RPB % 64 == 0)
    const int out_row0 = batch * OBS + out_off + (gm0 - batch * RPB);

    const int tx = t & 15, ty = t >> 4;

    float acc[4][4] = {};

    for (int k0 = 0; k0 < K; k0 += KT) {
        // stage A tile: 64 rows x 32 k  (store transposed As[k][m])
        #pragma unroll
        for (int i = 0; i < 2; i++) {
            int vi = t + (i << 8);                     // 0..511
            int m  = vi >> 3;                          // 8 float4 per row
            int kq = (vi & 7) << 2;
            float4 a = *(const float4*)&A[(gm0 + m) * K + k0 + kq];
            As[kq + 0][m] = a.x; As[kq + 1][m] = a.y;
            As[kq + 2][m] = a.z; As[kq + 3][m] = a.w;
        }
        // stage B tile: 32 k x 64 n
        #pragma unroll
        for (int i = 0; i < 2; i++) {
            int vi = t + (i << 8);
            int kk = vi >> 4;                          // 16 float4 per row
            int nq = (vi & 15) << 2;
            float4 b = *(const float4*)&W[(k0 + kk) * N + gn0 + nq];
            *(float4*)&Bs[kk][nq] = b;
        }
        __syncthreads();

        #pragma unroll
        for (int k = 0; k < KT; k++) {
            float4 a4 = *(const float4*)&As[k][ty << 2];
            float4 b4 = *(const float4*)&Bs[k][tx << 2];
            float av[4] = {a4.x, a4.y, a4.z, a4.w};
            float bv[4] = {b4.x, b4.y, b4.z, b4.w};
            #pragma unroll
            for (int i = 0; i < 4; i++)
                #pragma unroll
                for (int j = 0; j < 4; j++)
                    acc[i][j] += av[i] * bv[j];
        }
        __syncthreads();
    }

    float4 b4 = *(const float4*)&bias[gn0 + (tx << 2)];
    #pragma unroll
    for (int i = 0; i < 4; i++) {
        int row = out_row0 + (ty << 2) + i;
        float4 r;
        r.x = acc[i][0] + b4.x;
        r.y = acc[i][1] + b4.y;
        r.z = acc[i][2] + b4.z;
        r.w = acc[i][3] + b4.w;
        *(float4*)&out[row * N + gn0 + (tx << 2)] = r;
    }
}

// ---------------------------------------------------------------------------
// Flash attention: one block = (b, h, 16 q-rows), 256 threads = 4 waves.
// Wave w owns q-rows 4w..4w+3: its 64 lanes hold one j-column each, so row
// max/sum are pure wave-level shfl_xor butterflies; m/l live redundantly in
// registers of every lane of the owning wave (no cross-wave softmax traffic).
// P transposes to the PV accumulator layout via an intra-wave LDS round-trip
// (no extra barrier needed: same-wave DS dependency -> compiler lgkmcnt).
// Accumulator: thread t owns row r=t>>4, cols 4*(t&15)+{0..3} and 64+same.
// ---------------------------------------------------------------------------
__global__ __launch_bounds__(256) void attn_kernel(
    const float* __restrict__ qb, const float* __restrict__ kb,
    const float* __restrict__ vb, const int* __restrict__ mask1,
    const int* __restrict__ mask2, float* __restrict__ ab)
{
    __shared__ float Qs[16][68];
    __shared__ float Ks[64][68];
    __shared__ float Vs[64][132];
    __shared__ float Ps[16][68];

    const int t   = threadIdx.x;
    const int bid = blockIdx.x;
    const int b   = bid >> 9;          // / (H*64)
    const int h   = (bid >> 6) & 7;
    const int q0  = (bid & 63) << 4;

    // stage Q (pre-scaled by DH^-0.5 = 0.125); rows written intra-wave
    {
        int r = t >> 4, dq = (t & 15) << 2;
        float4 a = *(const float4*)&qb[(b * 1024 + q0 + r) * 512 + h * 64 + dq];
        Qs[r][dq + 0] = a.x * 0.125f; Qs[r][dq + 1] = a.y * 0.125f;
        Qs[r][dq + 2] = a.z * 0.125f; Qs[r][dq + 3] = a.w * 0.125f;
    }

    const int lane  = t & 63, w = t >> 6;
    const int r_acc = t >> 4, k_acc = r_acc & 3;
    const int c0    = (t & 15) << 2;

    float4 acc0 = {0.f, 0.f, 0.f, 0.f}, acc1 = {0.f, 0.f, 0.f, 0.f};
    float m_r[4] = {-1e30f, -1e30f, -1e30f, -1e30f};
    float l_r[4] = {0.f, 0.f, 0.f, 0.f};

    for (int jt = 0; jt < 32; jt++) {
        const int jg0 = jt << 6;
        __syncthreads();                       // protect K/V LDS reuse
        // stage K tile: 64 x 64
        #pragma unroll
        for (int i = 0; i < 4; i++) {
            int vi = t + (i << 8);
            int j = vi >> 4, dq = (vi & 15) << 2;
            float4 a = *(const float4*)&kb[(b * 2048 + jg0 + j) * 512 + h * 64 + dq];
            *(float4*)&Ks[j][dq] = a;
        }
        // stage V tile: 64 x 128
        #pragma unroll
        for (int i = 0; i < 8; i++) {
            int vi = t + (i << 8);
            int j = vi >> 5, cq = (vi & 31) << 2;
            float4 a = *(const float4*)&vb[(b * 2048 + jg0 + j) * 1024 + h * 128 + cq];
            *(float4*)&Vs[j][cq] = a;
        }
        __syncthreads();

        // scores: wave w, lane j -> rows 4w..4w+3
        float s[4] = {0.f, 0.f, 0.f, 0.f};
        #pragma unroll 8
        for (int d = 0; d < 64; d++) {
            float kd = Ks[lane][d];
            s[0] += Qs[4 * w + 0][d] * kd;
            s[1] += Qs[4 * w + 1][d] * kd;
            s[2] += Qs[4 * w + 2][d] * kd;
            s[3] += Qs[4 * w + 3][d] * kd;
        }
        const int jg = jg0 + lane;
        const int* mrow = (jg < 1024)
            ? &mask1[(b * 1024 + q0) * 1024 + jg]
            : &mask2[(b * 1024 + q0) * 1024 + (jg - 1024)];
        #pragma unroll
        for (int k = 0; k < 4; k++)
            if (!mrow[(4 * w + k) * 1024]) s[k] = -1e30f;

        // online softmax per row (wave-local)
        float alpha[4];
        #pragma unroll
        for (int k = 0; k < 4; k++) {
            float mt = s[k];
            #pragma unroll
            for (int off = 32; off; off >>= 1) mt = fmaxf(mt, __shfl_xor(mt, off, 64));
            float mn = fmaxf(m_r[k], mt);
            float ek = __expf(s[k] - mn);
            float lt = ek;
            #pragma unroll
            for (int off = 32; off; off >>= 1) lt += __shfl_xor(lt, off, 64);
            alpha[k] = __expf(m_r[k] - mn);
            l_r[k]   = l_r[k] * alpha[k] + lt;
            m_r[k]   = mn;
            Ps[4 * w + k][lane] = ek;          // intra-wave transpose via LDS
        }

        // rescale accumulators by this tile's alpha for own row
        float a_acc = (k_acc == 0) ? alpha[0] : (k_acc == 1) ? alpha[1]
                    : (k_acc == 2) ? alpha[2] : alpha[3];
        acc0.x *= a_acc; acc0.y *= a_acc; acc0.z *= a_acc; acc0.w *= a_acc;
        acc1.x *= a_acc; acc1.y *= a_acc; acc1.z *= a_acc; acc1.w *= a_acc;

        // PV: out[r][c] += sum_j P[r][j] * V[j][c]
        #pragma unroll 8
        for (int j2 = 0; j2 < 64; j2++) {
            float p = Ps[r_acc][j2];           // broadcast (same-wave data)
            float4 v0 = *(const float4*)&Vs[j2][c0];
            float4 v1 = *(const float4*)&Vs[j2][64 + c0];
            acc0.x += p * v0.x; acc0.y += p * v0.y;
            acc0.z += p * v0.z; acc0.w += p * v0.w;
            acc1.x += p * v1.x; acc1.y += p * v1.y;
            acc1.z += p * v1.z; acc1.w += p * v1.w;
        }
    }

    float l_f = (k_acc == 0) ? l_r[0] : (k_acc == 1) ? l_r[1]
              : (k_acc == 2) ? l_r[2] : l_r[3];
    float inv = 1.0f / l_f;
    int orow = (b * 1024 + q0 + r_acc) * 1024 + h * 128;
    acc0.x *= inv; acc0.y *= inv; acc0.z *= inv; acc0.w *= inv;
    acc1.x *= inv; acc1.y *= inv; acc1.z *= inv; acc1.w *= inv;
    *(float4*)&ab[orow + c0]      = acc0;
    *(float4*)&ab[orow + 64 + c0] = acc1;
}

// ---------------------------------------------------------------------------
extern "C" void kernel_launch(void* const* d_in, const int* in_sizes, int n_in,
                              void* d_out, int out_size, void* d_ws, size_t ws_size,
                              hipStream_t stream)
{
    const float* x        = (const float*)d_in[0];
    const float* context  = (const float*)d_in[1];
    const float* context2 = (const float*)d_in[2];
    const int*   mask1    = (const int*)d_in[3];
    const int*   mask2    = (const int*)d_in[4];
    const float* Wq  = (const float*)d_in[5];
    const float* bq  = (const float*)d_in[6];
    const float* Wk1 = (const float*)d_in[7];
    const float* bk1 = (const float*)d_in[8];
    const float* Wv1 = (const float*)d_in[9];
    const float* bv1 = (const float*)d_in[10];
    const float* Wk2 = (const float*)d_in[11];
    const float* bk2 = (const float*)d_in[12];
    const float* Wv2 = (const float*)d_in[13];
    const float* bv2 = (const float*)d_in[14];
    const float* Wo  = (const float*)d_in[15];
    const float* bo  = (const float*)d_in[16];
    float* out = (float*)d_out;

    float* ws = (float*)d_ws;
    float* qbuf = ws;                       // [2,1024,512]  = 1,048,576 f
    float* kbuf = qbuf + 1048576;           // [2,2048,512]  = 2,097,152 f
    float* vbuf = kbuf + 2097152;           // [2,2048,1024] = 4,194,304 f
    float* abuf = vbuf + 4194304;           // [2,1024,1024] = 2,097,152 f  (36 MB total)

    dim3 blk(256);
    // q = x @ Wq + bq                 M=2048 K=1024 N=512
    gemm_bias<<<dim3(8, 32),  blk, 0, stream>>>(x,        Wq,  bq,  qbuf, 2048, 1024, 512,  2048, 0,    0);
    // k = concat(ctx@Wk1, ctx2@Wk2)   -> kbuf[b, 0:1024 | 1024:2048, :]
    gemm_bias<<<dim3(8, 32),  blk, 0, stream>>>(context,  Wk1, bk1, kbuf, 2048, 1024, 512,  1024, 2048, 0);
    gemm_bias<<<dim3(8, 32),  blk, 0, stream>>>(context2, Wk2, bk2, kbuf, 2048, 1024, 512,  1024, 2048, 1024);
    // v = concat(ctx@Wv1, ctx2@Wv2)   -> vbuf
    gemm_bias<<<dim3(16, 32), blk, 0, stream>>>(context,  Wv1, bv1, vbuf, 2048, 1024, 1024, 1024, 2048, 0);
    gemm_bias<<<dim3(16, 32), blk, 0, stream>>>(context2, Wv2, bv2, vbuf, 2048, 1024, 1024, 1024, 2048, 1024);
    // flash attention -> abuf [2,1024,1024]
    attn_kernel<<<dim3(1024), blk, 0, stream>>>(qbuf, kbuf, vbuf, mask1, mask2, abuf);
    // out = abuf @ Wo + bo
    gemm_bias<<<dim3(16, 32), blk, 0, stream>>>(abuf,     Wo,  bo,  out,  2048, 1024, 1024, 2048, 0,    0);
}

// Round 2
// 267.883 us; speedup vs baseline: 3.1372x; 3.1372x over previous
//
#include <hip/hip_runtime.h>
#include <math.h>

typedef short bf16x8 __attribute__((ext_vector_type(8)));
typedef float f32x4  __attribute__((ext_vector_type(4)));

__device__ __forceinline__ unsigned short f2bf(float f) {
    unsigned int u = __builtin_bit_cast(unsigned int, f);
    u += 0x7FFFu + ((u >> 16) & 1u);
    return (unsigned short)(u >> 16);
}

// ---------------------------------------------------------------------------
// Cast 3 activation tensors fp32 -> bf16 (row-major), 8 elems/thread
// ---------------------------------------------------------------------------
__global__ __launch_bounds__(256) void cast3(
    const float* __restrict__ a0, const float* __restrict__ a1, const float* __restrict__ a2,
    unsigned short* __restrict__ o0, unsigned short* __restrict__ o1, unsigned short* __restrict__ o2)
{
    const int z = blockIdx.z;
    const float* a = z == 0 ? a0 : (z == 1 ? a1 : a2);
    unsigned short* o = z == 0 ? o0 : (z == 1 ? o1 : o2);
    size_t i = ((size_t)blockIdx.x * 256 + threadIdx.x) * 8;
    float4 x0 = *(const float4*)&a[i];
    float4 x1 = *(const float4*)&a[i + 4];
    uint4 pk;
    pk.x = (unsigned)f2bf(x0.x) | ((unsigned)f2bf(x0.y) << 16);
    pk.y = (unsigned)f2bf(x0.z) | ((unsigned)f2bf(x0.w) << 16);
    pk.z = (unsigned)f2bf(x1.x) | ((unsigned)f2bf(x1.y) << 16);
    pk.w = (unsigned)f2bf(x1.z) | ((unsigned)f2bf(x1.w) << 16);
    *(uint4*)&o[i] = pk;
}

// ---------------------------------------------------------------------------
// Cast+transpose 3 weights: W[K][N] fp32 -> Wt[N][K] bf16, 64x64 LDS tiles
// ---------------------------------------------------------------------------
__global__ __launch_bounds__(256) void cast_t3(
    const float* __restrict__ W0, const float* __restrict__ W1, const float* __restrict__ W2,
    unsigned short* __restrict__ T0, unsigned short* __restrict__ T1, unsigned short* __restrict__ T2,
    int K, int N)
{
    __shared__ float T[64][65];
    const int z = blockIdx.z;
    const float* W = z == 0 ? W0 : (z == 1 ? W1 : W2);
    unsigned short* O = z == 0 ? T0 : (z == 1 ? T1 : T2);
    const int n0 = blockIdx.x << 6, k0 = blockIdx.y << 6;
    const int t = threadIdx.x;
    #pragma unroll
    for (int i = 0; i < 4; i++) {
        int vi = t + (i << 8);
        int r = vi >> 4, c4 = (vi & 15) << 2;
        *(float4*)&T[r][c4] = *(const float4*)&W[(size_t)(k0 + r) * N + n0 + c4];
    }
    __syncthreads();
    #pragma unroll
    for (int i = 0; i < 4; i++) {
        int vi = t + (i << 8);
        int n = vi >> 4, k4 = (vi & 15) << 2;
        uint2 pk;
        pk.x = (unsigned)f2bf(T[k4 + 0][n]) | ((unsigned)f2bf(T[k4 + 1][n]) << 16);
        pk.y = (unsigned)f2bf(T[k4 + 2][n]) | ((unsigned)f2bf(T[k4 + 3][n]) << 16);
        *(uint2*)&O[(size_t)(n0 + n) * K + k0 + k4] = pk;
    }
}

// ---------------------------------------------------------------------------
// MFMA GEMM core: C[128x128] += A[M][K](bf16 rm) x Wt[N][K](bf16 rm)^T
// 256 thr = 4 waves in 2x2; wave = 4x4 tiles of 16x16x32. BK=32.
// A-frag: lane holds A[m=l15][k=quad*8+j]; B-frag mirror; C/D col=l15,row=quad*4+reg
// ---------------------------------------------------------------------------
__device__ __forceinline__ void gemm_core(
    const unsigned short* __restrict__ A,
    const unsigned short* __restrict__ Wt,
    int K, int gm0, int gn0,
    unsigned short (*As)[40], unsigned short (*Bs)[40],
    f32x4 (&acc)[4][4])
{
    const int t = threadIdx.x;
    const int lane = t & 63, w = t >> 6;
    const int wm = (w & 1) << 6, wn = (w >> 1) << 6;
    const int l15 = lane & 15, quad = lane >> 4;

    for (int k0 = 0; k0 < K; k0 += 32) {
        __syncthreads();
        #pragma unroll
        for (int i = 0; i < 2; i++) {
            int vi = t + (i << 8);
            int r = vi >> 2, c8 = (vi & 3) << 3;
            *(uint4*)&As[r][c8] = *(const uint4*)&A[(size_t)(gm0 + r) * K + k0 + c8];
            *(uint4*)&Bs[r][c8] = *(const uint4*)&Wt[(size_t)(gn0 + r) * K + k0 + c8];
        }
        __syncthreads();
        bf16x8 af[4], bg[4];
        #pragma unroll
        for (int i = 0; i < 4; i++)
            af[i] = *(const bf16x8*)&As[wm + (i << 4) + l15][quad << 3];
        #pragma unroll
        for (int j = 0; j < 4; j++)
            bg[j] = *(const bf16x8*)&Bs[wn + (j << 4) + l15][quad << 3];
        #pragma unroll
        for (int i = 0; i < 4; i++)
            #pragma unroll
            for (int j = 0; j < 4; j++)
                acc[i][j] = __builtin_amdgcn_mfma_f32_16x16x32_bf16(af[i], bg[j], acc[i][j], 0, 0, 0);
    }
}

// q,k1,k2 fused (z selects); bf16 row-major out with concat row remap
__global__ __launch_bounds__(256) void proj_qk(
    const unsigned short* __restrict__ xb, const unsigned short* __restrict__ c1b,
    const unsigned short* __restrict__ c2b,
    const unsigned short* __restrict__ Wqt, const unsigned short* __restrict__ Wk1t,
    const unsigned short* __restrict__ Wk2t,
    const float* __restrict__ bq, const float* __restrict__ bk1, const float* __restrict__ bk2,
    unsigned short* __restrict__ qbuf, unsigned short* __restrict__ kbuf)
{
    __shared__ unsigned short As[128][40];
    __shared__ unsigned short Bs[128][40];
    const int z = blockIdx.z;
    const unsigned short* A  = z == 0 ? xb  : (z == 1 ? c1b  : c2b);
    const unsigned short* Wt = z == 0 ? Wqt : (z == 1 ? Wk1t : Wk2t);
    const float* bias        = z == 0 ? bq  : (z == 1 ? bk1  : bk2);
    unsigned short* out      = z == 0 ? qbuf : kbuf;
    const int obs = z == 0 ? 1024 : 2048;
    const int off = z == 2 ? 1024 : 0;
    const int N = 512;
    const int gm0 = blockIdx.y << 7, gn0 = blockIdx.x << 7;

    f32x4 acc[4][4];
    #pragma unroll
    for (int i = 0; i < 4; i++)
        #pragma unroll
        for (int j = 0; j < 4; j++) acc[i][j] = (f32x4){0.f, 0.f, 0.f, 0.f};

    gemm_core(A, Wt, 1024, gm0, gn0, As, Bs, acc);

    const int lane = threadIdx.x & 63, w = threadIdx.x >> 6;
    const int wm = (w & 1) << 6, wn = (w >> 1) << 6;
    const int l15 = lane & 15, quad = lane >> 4;
    float bb[4];
    #pragma unroll
    for (int j = 0; j < 4; j++) bb[j] = bias[gn0 + wn + (j << 4) + l15];
    #pragma unroll
    for (int i = 0; i < 4; i++) {
        int mb = gm0 + wm + (i << 4) + (quad << 2);
        #pragma unroll
        for (int p = 0; p < 4; p++) {
            int m = mb + p;
            int orow = ((m >> 10) * obs) + off + (m & 1023);
            #pragma unroll
            for (int j = 0; j < 4; j++)
                out[(size_t)orow * N + gn0 + wn + (j << 4) + l15] = f2bf(acc[i][j][p] + bb[j]);
        }
    }
}

// v1,v2 fused; TRANSPOSED epilogue -> vT[B][1024][2048] bf16 (j = ctx row + off)
__global__ __launch_bounds__(256) void proj_v(
    const unsigned short* __restrict__ c1b, const unsigned short* __restrict__ c2b,
    const unsigned short* __restrict__ Wv1t, const unsigned short* __restrict__ Wv2t,
    const float* __restrict__ bv1, const float* __restrict__ bv2,
    unsigned short* __restrict__ vbT)
{
    __shared__ unsigned short As[128][40];
    __shared__ unsigned short Bs[128][40];
    const int z = blockIdx.z;
    const unsigned short* A  = z == 0 ? c1b  : c2b;
    const unsigned short* Wt = z == 0 ? Wv1t : Wv2t;
    const float* bias        = z == 0 ? bv1  : bv2;
    const int off = z == 0 ? 0 : 1024;
    const int gm0 = blockIdx.y << 7, gn0 = blockIdx.x << 7;

    f32x4 acc[4][4];
    #pragma unroll
    for (int i = 0; i < 4; i++)
        #pragma unroll
        for (int j = 0; j < 4; j++) acc[i][j] = (f32x4){0.f, 0.f, 0.f, 0.f};

    gemm_core(A, Wt, 1024, gm0, gn0, As, Bs, acc);

    const int lane = threadIdx.x & 63, w = threadIdx.x >> 6;
    const int wm = (w & 1) << 6, wn = (w >> 1) << 6;
    const int l15 = lane & 15, quad = lane >> 4;
    float bb[4];
    #pragma unroll
    for (int j = 0; j < 4; j++) bb[j] = bias[gn0 + wn + (j << 4) + l15];
    #pragma unroll
    for (int i = 0; i < 4; i++) {
        int mb = gm0 + wm + (i << 4) + (quad << 2);
        int b = mb >> 10;
        int jj = (mb & 1023) + off;
        #pragma unroll
        for (int j = 0; j < 4; j++) {
            int n = gn0 + wn + (j << 4) + l15;
            unsigned long long pk = 0;
            #pragma unroll
            for (int p = 0; p < 4; p++)
                pk |= (unsigned long long)f2bf(acc[i][j][p] + bb[j]) << (16 * p);
            *(unsigned long long*)&vbT[((size_t)b * 1024 + n) * 2048 + jj] = pk;
        }
    }
}

// final: out = abuf(bf16) @ Wot^T + bo, fp32 out
__global__ __launch_bounds__(256) void gemm_out(
    const unsigned short* __restrict__ abuf, const unsigned short* __restrict__ Wot,
    const float* __restrict__ bo, float* __restrict__ out)
{
    __shared__ unsigned short As[128][40];
    __shared__ unsigned short Bs[128][40];
    const int gm0 = blockIdx.y << 7, gn0 = blockIdx.x << 7;

    f32x4 acc[4][4];
    #pragma unroll
    for (int i = 0; i < 4; i++)
        #pragma unroll
        for (int j = 0; j < 4; j++) acc[i][j] = (f32x4){0.f, 0.f, 0.f, 0.f};

    gemm_core(abuf, Wot, 1024, gm0, gn0, As, Bs, acc);

    const int lane = threadIdx.x & 63, w = threadIdx.x >> 6;
    const int wm = (w & 1) << 6, wn = (w >> 1) << 6;
    const int l15 = lane & 15, quad = lane >> 4;
    float bb[4];
    #pragma unroll
    for (int j = 0; j < 4; j++) bb[j] = bo[gn0 + wn + (j << 4) + l15];
    #pragma unroll
    for (int i = 0; i < 4; i++) {
        int mb = gm0 + wm + (i << 4) + (quad << 2);
        #pragma unroll
        for (int p = 0; p < 4; p++)
            #pragma unroll
            for (int j = 0; j < 4; j++)
                out[(size_t)(mb + p) * 1024 + gn0 + wn + (j << 4) + l15] = acc[i][j][p] + bb[j];
    }
}

// ---------------------------------------------------------------------------
// MFMA flash attention. Block=(b,h,64 q rows), 4 waves x 16 q rows.
// QK^T and PV via 16x16x32 bf16 MFMA; online softmax in quad groups of the
// C-layout; P through LDS intra-wave (layout change C->A).
// ---------------------------------------------------------------------------
__global__ __launch_bounds__(256) void attn_mfma(
    const unsigned short* __restrict__ qbuf, const unsigned short* __restrict__ kbuf,
    const unsigned short* __restrict__ vbT, const int* __restrict__ mask1,
    const int* __restrict__ mask2, unsigned short* __restrict__ abuf)
{
    __shared__ unsigned short Ks[64][72];    // [j][d]
    __shared__ unsigned short VsT[128][72];  // [c][j]
    __shared__ unsigned short Ps[64][72];    // [q][j]

    const int t = threadIdx.x;
    const int bid = blockIdx.x;
    const int h = bid & 7, qt = (bid >> 3) & 15, b = bid >> 7;
    const int q0 = qt << 6;
    const int lane = t & 63, w = t >> 6;
    const int l15 = lane & 15, quad = lane >> 4;

    // loop-invariant Q A-frags (rows w*16+l15, k=quad*8 / +32)
    const unsigned short* qrow = qbuf + (((size_t)(b << 10) + q0 + (w << 4) + l15) << 9) + (h << 6);
    const bf16x8 aq0 = *(const bf16x8*)&qrow[quad << 3];
    const bf16x8 aq1 = *(const bf16x8*)&qrow[32 + (quad << 3)];

    f32x4 acc[8];
    #pragma unroll
    for (int ct = 0; ct < 8; ct++) acc[ct] = (f32x4){0.f, 0.f, 0.f, 0.f};
    float m_p[4] = {-3.0e38f, -3.0e38f, -3.0e38f, -3.0e38f};
    float l_p[4] = {0.f, 0.f, 0.f, 0.f};

    const size_t kbase = (size_t)b << 20;                              // b*2048*512
    const size_t vbase = ((size_t)((b << 10) + (h << 7))) << 11;       // (b*1024+h*128)*2048
    const int* mb1 = mask1 + ((size_t)b << 20);
    const int* mb2 = mask2 + ((size_t)b << 20);
    const int qg = q0 + (w << 4) + (quad << 2);

    for (int jt = 0; jt < 32; jt++) {
        const int j0 = jt << 6;
        __syncthreads();
        #pragma unroll
        for (int i = 0; i < 2; i++) {
            int vi = t + (i << 8);
            int j = vi >> 3, c8 = (vi & 7) << 3;
            *(uint4*)&Ks[j][c8] = *(const uint4*)&kbuf[kbase + ((size_t)(j0 + j) << 9) + (h << 6) + c8];
        }
        #pragma unroll
        for (int i = 0; i < 4; i++) {
            int vi = t + (i << 8);
            int c = vi >> 3, j8 = (vi & 7) << 3;
            *(uint4*)&VsT[c][j8] = *(const uint4*)&vbT[vbase + ((size_t)c << 11) + j0 + j8];
        }
        __syncthreads();

        // S = Q K^T  (wave strip: 16q x 64j as 4 col tiles)
        f32x4 s[4];
        #pragma unroll
        for (int n = 0; n < 4; n++) {
            s[n] = (f32x4){0.f, 0.f, 0.f, 0.f};
            bf16x8 bk0 = *(const bf16x8*)&Ks[(n << 4) + l15][quad << 3];
            bf16x8 bk1 = *(const bf16x8*)&Ks[(n << 4) + l15][32 + (quad << 3)];
            s[n] = __builtin_amdgcn_mfma_f32_16x16x32_bf16(aq0, bk0, s[n], 0, 0, 0);
            s[n] = __builtin_amdgcn_mfma_f32_16x16x32_bf16(aq1, bk1, s[n], 0, 0, 0);
        }

        // scale + mask
        const int* mb_ = (j0 < 1024) ? mb1 : mb2;
        const int jh = (j0 & 1023) + l15;
        #pragma unroll
        for (int p = 0; p < 4; p++) {
            const int* mrow = mb_ + (size_t)(qg + p) * 1024 + jh;
            #pragma unroll
            for (int n = 0; n < 4; n++) {
                float sv = s[n][p] * 0.125f;
                s[n][p] = mrow[n << 4] ? sv : -3.0e38f;
            }
        }

        // online softmax per row (rows quad*4+p, 16-lane quad groups)
        float alpha[4];
        #pragma unroll
        for (int p = 0; p < 4; p++) {
            float mt = fmaxf(fmaxf(s[0][p], s[1][p]), fmaxf(s[2][p], s[3][p]));
            #pragma unroll
            for (int o = 1; o < 16; o <<= 1) mt = fmaxf(mt, __shfl_xor(mt, o, 64));
            float mn = fmaxf(m_p[p], mt);
            float e0 = __expf(s[0][p] - mn), e1 = __expf(s[1][p] - mn);
            float e2 = __expf(s[2][p] - mn), e3 = __expf(s[3][p] - mn);
            float ls = e0 + e1 + e2 + e3;
            #pragma unroll
            for (int o = 1; o < 16; o <<= 1) ls += __shfl_xor(ls, o, 64);
            alpha[p] = __expf(m_p[p] - mn);
            l_p[p] = l_p[p] * alpha[p] + ls;
            m_p[p] = mn;
            int pr = (w << 4) + (quad << 2) + p;
            Ps[pr][l15]      = f2bf(e0);
            Ps[pr][16 + l15] = f2bf(e1);
            Ps[pr][32 + l15] = f2bf(e2);
            Ps[pr][48 + l15] = f2bf(e3);
        }

        // rescale O
        #pragma unroll
        for (int ct = 0; ct < 8; ct++)
            #pragma unroll
            for (int p = 0; p < 4; p++) acc[ct][p] *= alpha[p];

        // PV: A-frags from Ps (intra-wave RAW), B-frags from VsT
        bf16x8 ap0 = *(const bf16x8*)&Ps[(w << 4) + l15][quad << 3];
        bf16x8 ap1 = *(const bf16x8*)&Ps[(w << 4) + l15][32 + (quad << 3)];
        #pragma unroll
        for (int ct = 0; ct < 8; ct++) {
            bf16x8 bv0 = *(const bf16x8*)&VsT[(ct << 4) + l15][quad << 3];
            bf16x8 bv1 = *(const bf16x8*)&VsT[(ct << 4) + l15][32 + (quad << 3)];
            acc[ct] = __builtin_amdgcn_mfma_f32_16x16x32_bf16(ap0, bv0, acc[ct], 0, 0, 0);
            acc[ct] = __builtin_amdgcn_mfma_f32_16x16x32_bf16(ap1, bv1, acc[ct], 0, 0, 0);
        }
    }

    #pragma unroll
    for (int p = 0; p < 4; p++) {
        float inv = 1.0f / l_p[p];
        int qrow_g = (b << 10) + q0 + (w << 4) + (quad << 2) + p;
        size_t base = ((size_t)qrow_g << 10) + (h << 7);
        #pragma unroll
        for (int ct = 0; ct < 8; ct++)
            abuf[base + (ct << 4) + l15] = f2bf(acc[ct][p] * inv);
    }
}

// ---------------------------------------------------------------------------
extern "C" void kernel_launch(void* const* d_in, const int* in_sizes, int n_in,
                              void* d_out, int out_size, void* d_ws, size_t ws_size,
                              hipStream_t stream)
{
    const float* x        = (const float*)d_in[0];
    const float* context  = (const float*)d_in[1];
    const float* context2 = (const float*)d_in[2];
    const int*   mask1    = (const int*)d_in[3];
    const int*   mask2    = (const int*)d_in[4];
    const float* Wq  = (const float*)d_in[5];
    const float* bq  = (const float*)d_in[6];
    const float* Wk1 = (const float*)d_in[7];
    const float* bk1 = (const float*)d_in[8];
    const float* Wv1 = (const float*)d_in[9];
    const float* bv1 = (const float*)d_in[10];
    const float* Wk2 = (const float*)d_in[11];
    const float* bk2 = (const float*)d_in[12];
    const float* Wv2 = (const float*)d_in[13];
    const float* bv2 = (const float*)d_in[14];
    const float* Wo  = (const float*)d_in[15];
    const float* bo  = (const float*)d_in[16];
    float* out = (float*)d_out;

    unsigned short* ws = (unsigned short*)d_ws;
    const size_t M1 = 1u << 20;                 // 1M ushorts
    unsigned short* xb   = ws;                  // 2M
    unsigned short* c1b  = ws + 2 * M1;         // 2M
    unsigned short* c2b  = ws + 4 * M1;         // 2M
    unsigned short* Wqt  = ws + 6 * M1;         // 512K
    unsigned short* Wk1t = Wqt + 524288;
    unsigned short* Wk2t = Wk1t + 524288;
    unsigned short* Wv1t = Wk2t + 524288;       // 1M
    unsigned short* Wv2t = Wv1t + M1;
    unsigned short* Wot  = Wv2t + M1;
    unsigned short* qbuf = Wot + M1;            // [2048][512]   1M
    unsigned short* kbuf = qbuf + M1;           // [2][2048][512] 2M
    unsigned short* vbT  = kbuf + 2 * M1;       // [2][1024][2048] 4M
    unsigned short* abuf = vbT + 4 * M1;        // [2048][1024]  2M

    cast3  <<<dim3(1024, 1, 3), 256, 0, stream>>>(x, context, context2, xb, c1b, c2b);
    cast_t3<<<dim3(8, 16, 3),  256, 0, stream>>>(Wq, Wk1, Wk2, Wqt, Wk1t, Wk2t, 1024, 512);
    cast_t3<<<dim3(16, 16, 3), 256, 0, stream>>>(Wv1, Wv2, Wo, Wv1t, Wv2t, Wot, 1024, 1024);
    proj_qk<<<dim3(4, 16, 3),  256, 0, stream>>>(xb, c1b, c2b, Wqt, Wk1t, Wk2t, bq, bk1, bk2, qbuf, kbuf);
    proj_v <<<dim3(8, 16, 2),  256, 0, stream>>>(c1b, c2b, Wv1t, Wv2t, bv1, bv2, vbT);
    attn_mfma<<<dim3(256),     256, 0, stream>>>(qbuf, kbuf, vbT, mask1, mask2, abuf);
    gemm_out<<<dim3(8, 16),    256, 0, stream>>>(abuf, Wot, bo, out);
}

// Round 3
// 256.962 us; speedup vs baseline: 3.2705x; 1.0425x over previous
//
#include <hip/hip_runtime.h>
#include <math.h>

typedef short bf16x8 __attribute__((ext_vector_type(8)));
typedef float f32x4  __attribute__((ext_vector_type(4)));

__device__ __forceinline__ unsigned short f2bf(float f) {
    unsigned int u = __builtin_bit_cast(unsigned int, f);
    u += 0x7FFFu + ((u >> 16) & 1u);
    return (unsigned short)(u >> 16);
}

// async global->LDS, 16B per lane. LDS dest = wave-uniform base + lane*16.
__device__ __forceinline__ void gld16(const unsigned short* g, unsigned short* l) {
    __builtin_amdgcn_global_load_lds(
        (const __attribute__((address_space(1))) void*)g,
        (__attribute__((address_space(3))) void*)l, 16, 0, 0);
}

// ---------------------------------------------------------------------------
// Cast 3 activation tensors fp32 -> bf16 (row-major)
// ---------------------------------------------------------------------------
__global__ __launch_bounds__(256) void cast3(
    const float* __restrict__ a0, const float* __restrict__ a1, const float* __restrict__ a2,
    unsigned short* __restrict__ o0, unsigned short* __restrict__ o1, unsigned short* __restrict__ o2)
{
    const int z = blockIdx.z;
    const float* a = z == 0 ? a0 : (z == 1 ? a1 : a2);
    unsigned short* o = z == 0 ? o0 : (z == 1 ? o1 : o2);
    size_t i = ((size_t)blockIdx.x * 256 + threadIdx.x) * 8;
    float4 x0 = *(const float4*)&a[i];
    float4 x1 = *(const float4*)&a[i + 4];
    uint4 pk;
    pk.x = (unsigned)f2bf(x0.x) | ((unsigned)f2bf(x0.y) << 16);
    pk.y = (unsigned)f2bf(x0.z) | ((unsigned)f2bf(x0.w) << 16);
    pk.z = (unsigned)f2bf(x1.x) | ((unsigned)f2bf(x1.y) << 16);
    pk.w = (unsigned)f2bf(x1.z) | ((unsigned)f2bf(x1.w) << 16);
    *(uint4*)&o[i] = pk;
}

// ---------------------------------------------------------------------------
// Cast+transpose 3 weights: W[K][N] fp32 -> Wt[N][K] bf16
// ---------------------------------------------------------------------------
__global__ __launch_bounds__(256) void cast_t3(
    const float* __restrict__ W0, const float* __restrict__ W1, const float* __restrict__ W2,
    unsigned short* __restrict__ T0, unsigned short* __restrict__ T1, unsigned short* __restrict__ T2,
    int K, int N)
{
    __shared__ float T[64][65];
    const int z = blockIdx.z;
    const float* W = z == 0 ? W0 : (z == 1 ? W1 : W2);
    unsigned short* O = z == 0 ? T0 : (z == 1 ? T1 : T2);
    const int n0 = blockIdx.x << 6, k0 = blockIdx.y << 6;
    const int t = threadIdx.x;
    #pragma unroll
    for (int i = 0; i < 4; i++) {
        int vi = t + (i << 8);
        int r = vi >> 4, c4 = (vi & 15) << 2;
        *(float4*)&T[r][c4] = *(const float4*)&W[(size_t)(k0 + r) * N + n0 + c4];
    }
    __syncthreads();
    #pragma unroll
    for (int i = 0; i < 4; i++) {
        int vi = t + (i << 8);
        int n = vi >> 4, k4 = (vi & 15) << 2;
        uint2 pk;
        pk.x = (unsigned)f2bf(T[k4 + 0][n]) | ((unsigned)f2bf(T[k4 + 1][n]) << 16);
        pk.y = (unsigned)f2bf(T[k4 + 2][n]) | ((unsigned)f2bf(T[k4 + 3][n]) << 16);
        *(uint2*)&O[(size_t)(n0 + n) * K + k0 + k4] = pk;
    }
}

// ---------------------------------------------------------------------------
// Pack masks to bits: mpk[b*1024+q][32] uint64; word w covers j=64w..64w+63
// (w<16 from mask1, else mask2). One wave per (b,q) row.
// ---------------------------------------------------------------------------
__global__ __launch_bounds__(256) void pack_mask(
    const int* __restrict__ mask1, const int* __restrict__ mask2,
    unsigned long long* __restrict__ mpk)
{
    int wid = (blockIdx.x << 2) + (threadIdx.x >> 6);   // row 0..2047
    int lane = threadIdx.x & 63;
    const int* m1 = mask1 + ((size_t)wid << 10);
    const int* m2 = mask2 + ((size_t)wid << 10);
    unsigned long long* o = mpk + ((size_t)wid << 5);
    #pragma unroll
    for (int win = 0; win < 16; win++) {
        unsigned long long bal = __ballot(m1[(win << 6) + lane] != 0);
        if (lane == 0) o[win] = bal;
    }
    #pragma unroll
    for (int win = 0; win < 16; win++) {
        unsigned long long bal = __ballot(m2[(win << 6) + lane] != 0);
        if (lane == 0) o[16 + win] = bal;
    }
}

// ---------------------------------------------------------------------------
// m97-style MFMA GEMM core: C[128x128] += A[M][K] x Wt[N][K]^T, BK=32,
// global_load_lds width-16 staging into unpadded [128][32] LDS.
// ---------------------------------------------------------------------------
__device__ __forceinline__ void gemm_core(
    const unsigned short* __restrict__ A,
    const unsigned short* __restrict__ Wt,
    int K, int gm0, int gn0,
    unsigned short (*As)[32], unsigned short (*Bs)[32],
    f32x4 (&acc)[4][4])
{
    const int t = threadIdx.x;
    const int lane = t & 63, w = t >> 6;
    const int wm = (w & 1) << 6, wn = (w >> 1) << 6;
    const int l15 = lane & 15, quad = lane >> 4;

    for (int k0 = 0; k0 < K; k0 += 32) {
        __syncthreads();
        #pragma unroll
        for (int i = 0; i < 2; i++) {
            int r0 = (i << 6) + (w << 4);
            int ra = r0 + (lane >> 2);
            int kc = (lane & 3) << 3;
            gld16(&A [(size_t)(gm0 + ra) * K + k0 + kc], &As[r0][0] + ((size_t)lane << 3));
            gld16(&Wt[(size_t)(gn0 + ra) * K + k0 + kc], &Bs[r0][0] + ((size_t)lane << 3));
        }
        __syncthreads();
        bf16x8 af[4], bg[4];
        #pragma unroll
        for (int i = 0; i < 4; i++)
            af[i] = *(const bf16x8*)&As[wm + (i << 4) + l15][quad << 3];
        #pragma unroll
        for (int j = 0; j < 4; j++)
            bg[j] = *(const bf16x8*)&Bs[wn + (j << 4) + l15][quad << 3];
        #pragma unroll
        for (int i = 0; i < 4; i++)
            #pragma unroll
            for (int j = 0; j < 4; j++)
                acc[i][j] = __builtin_amdgcn_mfma_f32_16x16x32_bf16(af[i], bg[j], acc[i][j], 0, 0, 0);
    }
}

// ---------------------------------------------------------------------------
// All 5 projections in one launch. Flat grid of 448 blocks:
// [0,64)=q, [64,128)=k1, [128,192)=k2, [192,320)=v1, [320,448)=v2.
// ---------------------------------------------------------------------------
__global__ __launch_bounds__(256) void proj_all(
    const unsigned short* __restrict__ xb, const unsigned short* __restrict__ c1b,
    const unsigned short* __restrict__ c2b,
    const unsigned short* __restrict__ Wqt, const unsigned short* __restrict__ Wk1t,
    const unsigned short* __restrict__ Wk2t, const unsigned short* __restrict__ Wv1t,
    const unsigned short* __restrict__ Wv2t,
    const float* __restrict__ bq, const float* __restrict__ bk1, const float* __restrict__ bk2,
    const float* __restrict__ bv1, const float* __restrict__ bv2,
    unsigned short* __restrict__ qbuf, unsigned short* __restrict__ kbuf,
    unsigned short* __restrict__ vbT)
{
    __shared__ unsigned short As[128][32];
    __shared__ unsigned short Bs[128][32];
    const int bid = blockIdx.x;
    int z, bx, by;
    if (bid < 192) { z = bid >> 6; int l = bid & 63; by = l >> 2; bx = l & 3; }
    else { int l = bid - 192; z = 3 + (l >> 7); l &= 127; by = l >> 3; bx = l & 7; }
    const unsigned short* A  = (z == 0) ? xb : (z == 1 || z == 3) ? c1b : c2b;
    const unsigned short* Wt = (z == 0) ? Wqt : (z == 1) ? Wk1t : (z == 2) ? Wk2t
                             : (z == 3) ? Wv1t : Wv2t;
    const float* bias = (z == 0) ? bq : (z == 1) ? bk1 : (z == 2) ? bk2
                      : (z == 3) ? bv1 : bv2;
    const int gm0 = by << 7, gn0 = bx << 7;

    f32x4 acc[4][4];
    #pragma unroll
    for (int i = 0; i < 4; i++)
        #pragma unroll
        for (int j = 0; j < 4; j++) acc[i][j] = (f32x4){0.f, 0.f, 0.f, 0.f};

    gemm_core(A, Wt, 1024, gm0, gn0, As, Bs, acc);

    const int lane = threadIdx.x & 63, w = threadIdx.x >> 6;
    const int wm = (w & 1) << 6, wn = (w >> 1) << 6;
    const int l15 = lane & 15, quad = lane >> 4;
    float bb[4];
    #pragma unroll
    for (int j = 0; j < 4; j++) bb[j] = bias[gn0 + wn + (j << 4) + l15];

    if (z < 3) {
        unsigned short* out = (z == 0) ? qbuf : kbuf;
        const int obs = (z == 0) ? 1024 : 2048;
        const int off = (z == 2) ? 1024 : 0;
        #pragma unroll
        for (int i = 0; i < 4; i++) {
            int mb = gm0 + wm + (i << 4) + (quad << 2);
            #pragma unroll
            for (int p = 0; p < 4; p++) {
                int m = mb + p;
                int orow = ((m >> 10) * obs) + off + (m & 1023);
                #pragma unroll
                for (int j = 0; j < 4; j++)
                    out[(size_t)orow * 512 + gn0 + wn + (j << 4) + l15] = f2bf(acc[i][j][p] + bb[j]);
            }
        }
    } else {
        const int off = (z == 3) ? 0 : 1024;
        #pragma unroll
        for (int i = 0; i < 4; i++) {
            int mb = gm0 + wm + (i << 4) + (quad << 2);
            int b = mb >> 10;
            int jj = (mb & 1023) + off;
            #pragma unroll
            for (int j = 0; j < 4; j++) {
                int n = gn0 + wn + (j << 4) + l15;
                unsigned long long pk = 0;
                #pragma unroll
                for (int p = 0; p < 4; p++)
                    pk |= (unsigned long long)f2bf(acc[i][j][p] + bb[j]) << (16 * p);
                *(unsigned long long*)&vbT[((size_t)b * 1024 + n) * 2048 + jj] = pk;
            }
        }
    }
}

// ---------------------------------------------------------------------------
// final: out = abuf(bf16) @ Wot^T + bo, fp32 out
// ---------------------------------------------------------------------------
__global__ __launch_bounds__(256) void gemm_out(
    const unsigned short* __restrict__ abuf, const unsigned short* __restrict__ Wot,
    const float* __restrict__ bo, float* __restrict__ out)
{
    __shared__ unsigned short As[128][32];
    __shared__ unsigned short Bs[128][32];
    const int gm0 = blockIdx.y << 7, gn0 = blockIdx.x << 7;

    f32x4 acc[4][4];
    #pragma unroll
    for (int i = 0; i < 4; i++)
        #pragma unroll
        for (int j = 0; j < 4; j++) acc[i][j] = (f32x4){0.f, 0.f, 0.f, 0.f};

    gemm_core(abuf, Wot, 1024, gm0, gn0, As, Bs, acc);

    const int lane = threadIdx.x & 63, w = threadIdx.x >> 6;
    const int wm = (w & 1) << 6, wn = (w >> 1) << 6;
    const int l15 = lane & 15, quad = lane >> 4;
    float bb[4];
    #pragma unroll
    for (int j = 0; j < 4; j++) bb[j] = bo[gn0 + wn + (j << 4) + l15];
    #pragma unroll
    for (int i = 0; i < 4; i++) {
        int mb = gm0 + wm + (i << 4) + (quad << 2);
        #pragma unroll
        for (int p = 0; p < 4; p++)
            #pragma unroll
            for (int j = 0; j < 4; j++)
                out[(size_t)(mb + p) * 1024 + gn0 + wn + (j << 4) + l15] = acc[i][j][p] + bb[j];
    }
}

// ---------------------------------------------------------------------------
// MFMA flash attention, j-split x2. Block=(hs, b, h, 64 q rows), 512 blocks.
// j-tile=128. XOR-swizzled LDS (chunk ^= row&7) kills bank conflicts.
// Bit-packed masks. Outputs unnormalized O + (m,l) per row for combine.
// ---------------------------------------------------------------------------
__global__ __launch_bounds__(256) void attn_mfma(
    const unsigned short* __restrict__ qbuf, const unsigned short* __restrict__ kbuf,
    const unsigned short* __restrict__ vbT, const unsigned long long* __restrict__ mpk,
    float* __restrict__ Opart, float* __restrict__ ml)
{
    __shared__ unsigned short Ks[128][64];    // [j][d]   swizzled
    __shared__ unsigned short VsT[128][128];  // [feat][j] swizzled
    __shared__ unsigned short Ps[64][128];    // [q][j]   swizzled

    const int t = threadIdx.x;
    const int bid = blockIdx.x;
    const int hs = bid >> 8, r = bid & 255;
    const int h = r & 7, qt = (r >> 3) & 15, b = r >> 7;
    const int q0 = qt << 6;
    const int lane = t & 63, w = t >> 6, l15 = lane & 15, quad = lane >> 4;

    const unsigned short* qrow = qbuf + (((size_t)(b << 10) + q0 + (w << 4) + l15) << 9) + (h << 6);
    const bf16x8 aq0 = *(const bf16x8*)&qrow[quad << 3];
    const bf16x8 aq1 = *(const bf16x8*)&qrow[32 + (quad << 3)];

    f32x4 acc[8];
    #pragma unroll
    for (int ct = 0; ct < 8; ct++) acc[ct] = (f32x4){0.f, 0.f, 0.f, 0.f};
    float m_p[4] = {-3.0e38f, -3.0e38f, -3.0e38f, -3.0e38f};
    float l_p[4] = {0.f, 0.f, 0.f, 0.f};

    const size_t kbase = (size_t)b << 20;
    const size_t vbase = ((size_t)((b << 10) + (h << 7))) << 11;
    const int qg = q0 + (w << 4) + (quad << 2);
    const unsigned long long* mrow0 = mpk + (((size_t)(b << 10) + qg) << 5);

    for (int jt = 0; jt < 8; jt++) {
        const int j0 = (hs << 10) + (jt << 7);
        __syncthreads();
        #pragma unroll
        for (int i = 0; i < 4; i++) {             // K: 128 x 64
            int vi = t + (i << 8);
            int row = vi >> 3, c = vi & 7;
            *(uint4*)&Ks[row][(c ^ (row & 7)) << 3] =
                *(const uint4*)&kbuf[kbase + ((size_t)(j0 + row) << 9) + (h << 6) + (c << 3)];
        }
        #pragma unroll
        for (int i = 0; i < 8; i++) {             // V^T: 128 feat x 128 j
            int vi = t + (i << 8);
            int f = vi >> 4, c = vi & 15;
            int sc = (c & 8) | ((c & 7) ^ (f & 7));
            *(uint4*)&VsT[f][sc << 3] =
                *(const uint4*)&vbT[vbase + ((size_t)f << 11) + j0 + (c << 3)];
        }
        __syncthreads();

        // S = Q K^T : 16q x 128j per wave
        f32x4 s[8];
        #pragma unroll
        for (int n = 0; n < 8; n++) {
            int rowk = (n << 4) + l15;
            bf16x8 bk0 = *(const bf16x8*)&Ks[rowk][(quad ^ (l15 & 7)) << 3];
            bf16x8 bk1 = *(const bf16x8*)&Ks[rowk][((quad | 4) ^ (l15 & 7)) << 3];
            s[n] = (f32x4){0.f, 0.f, 0.f, 0.f};
            s[n] = __builtin_amdgcn_mfma_f32_16x16x32_bf16(aq0, bk0, s[n], 0, 0, 0);
            s[n] = __builtin_amdgcn_mfma_f32_16x16x32_bf16(aq1, bk1, s[n], 0, 0, 0);
        }

        // scale + mask via packed bits
        const int wbase = j0 >> 6;
        #pragma unroll
        for (int p = 0; p < 4; p++) {
            const unsigned long long* mr = mrow0 + ((size_t)p << 5);
            unsigned long long w0 = mr[wbase], w1 = mr[wbase + 1];
            #pragma unroll
            for (int n = 0; n < 8; n++) {
                unsigned long long wd = (n < 4) ? w0 : w1;
                int bit = ((n & 3) << 4) + l15;
                float sv = s[n][p] * 0.125f;
                s[n][p] = ((wd >> bit) & 1ull) ? sv : -3.0e38f;
            }
        }

        // online softmax (16-lane quad groups own rows)
        float alpha[4];
        #pragma unroll
        for (int p = 0; p < 4; p++) {
            float mt = s[0][p];
            #pragma unroll
            for (int n = 1; n < 8; n++) mt = fmaxf(mt, s[n][p]);
            #pragma unroll
            for (int o = 1; o < 16; o <<= 1) mt = fmaxf(mt, __shfl_xor(mt, o, 64));
            float mn = fmaxf(m_p[p], mt);
            float e[8], ls = 0.f;
            #pragma unroll
            for (int n = 0; n < 8; n++) { e[n] = __expf(s[n][p] - mn); ls += e[n]; }
            #pragma unroll
            for (int o = 1; o < 16; o <<= 1) ls += __shfl_xor(ls, o, 64);
            alpha[p] = __expf(m_p[p] - mn);
            l_p[p] = l_p[p] * alpha[p] + ls;
            m_p[p] = mn;
            int pr = (w << 4) + (quad << 2) + p;
            #pragma unroll
            for (int n = 0; n < 8; n++) {
                int c = (n << 1) + (l15 >> 3);
                int sc = (c & 8) | ((c & 7) ^ (pr & 7));
                Ps[pr][(sc << 3) + (l15 & 7)] = f2bf(e[n]);
            }
        }

        #pragma unroll
        for (int ct = 0; ct < 8; ct++)
            #pragma unroll
            for (int p = 0; p < 4; p++) acc[ct][p] *= alpha[p];

        // O += P V  (A from Ps, B from VsT; intra-wave RAW through LDS)
        bf16x8 ap[4];
        #pragma unroll
        for (int kk = 0; kk < 4; kk++) {
            int c = (kk << 2) + quad;
            int sc = (c & 8) | ((c & 7) ^ (l15 & 7));
            ap[kk] = *(const bf16x8*)&Ps[(w << 4) + l15][sc << 3];
        }
        #pragma unroll
        for (int ct = 0; ct < 8; ct++) {
            int fv = (ct << 4) + l15;
            #pragma unroll
            for (int kk = 0; kk < 4; kk++) {
                int c = (kk << 2) + quad;
                int sc = (c & 8) | ((c & 7) ^ (l15 & 7));
                bf16x8 bv = *(const bf16x8*)&VsT[fv][sc << 3];
                acc[ct] = __builtin_amdgcn_mfma_f32_16x16x32_bf16(ap[kk], bv, acc[ct], 0, 0, 0);
            }
        }
    }

    #pragma unroll
    for (int p = 0; p < 4; p++) {
        int q = q0 + (w << 4) + (quad << 2) + p;
        size_t idx = (size_t)(hs << 14) + (b << 13) + (h << 10) + q;
        #pragma unroll
        for (int ct = 0; ct < 8; ct++)
            Opart[(idx << 7) + (ct << 4) + l15] = acc[ct][p];
        if (l15 == 0) {
            ml[(idx << 1) + 0] = m_p[p];
            ml[(idx << 1) + 1] = l_p[p];
        }
    }
}

// ---------------------------------------------------------------------------
// Combine the two j-halves -> abuf bf16
// ---------------------------------------------------------------------------
__global__ __launch_bounds__(256) void attn_combine(
    const float* __restrict__ Opart, const float* __restrict__ ml,
    unsigned short* __restrict__ abuf)
{
    int id = (blockIdx.x << 8) + threadIdx.x;       // 524288
    int bhq = id >> 5, c4 = (id & 31) << 2;
    float2 ml0 = ((const float2*)ml)[bhq];
    float2 ml1 = ((const float2*)ml)[16384 + bhq];
    float M = fmaxf(ml0.x, ml1.x);
    float a0 = __expf(ml0.x - M), a1 = __expf(ml1.x - M);
    float inv = 1.0f / (ml0.y * a0 + ml1.y * a1);
    float4 o0 = *(const float4*)&Opart[((size_t)bhq << 7) + c4];
    float4 o1 = *(const float4*)&Opart[((size_t)(16384 + bhq) << 7) + c4];
    int b = bhq >> 13, hh = (bhq >> 10) & 7, q = bhq & 1023;
    float r0 = (o0.x * a0 + o1.x * a1) * inv;
    float r1 = (o0.y * a0 + o1.y * a1) * inv;
    float r2 = (o0.z * a0 + o1.z * a1) * inv;
    float r3 = (o0.w * a0 + o1.w * a1) * inv;
    unsigned long long pk = (unsigned long long)f2bf(r0)
        | ((unsigned long long)f2bf(r1) << 16)
        | ((unsigned long long)f2bf(r2) << 32)
        | ((unsigned long long)f2bf(r3) << 48);
    *(unsigned long long*)&abuf[((size_t)((b << 10) + q) << 10) + (hh << 7) + c4] = pk;
}

// ---------------------------------------------------------------------------
extern "C" void kernel_launch(void* const* d_in, const int* in_sizes, int n_in,
                              void* d_out, int out_size, void* d_ws, size_t ws_size,
                              hipStream_t stream)
{
    const float* x        = (const float*)d_in[0];
    const float* context  = (const float*)d_in[1];
    const float* context2 = (const float*)d_in[2];
    const int*   mask1    = (const int*)d_in[3];
    const int*   mask2    = (const int*)d_in[4];
    const float* Wq  = (const float*)d_in[5];
    const float* bq  = (const float*)d_in[6];
    const float* Wk1 = (const float*)d_in[7];
    const float* bk1 = (const float*)d_in[8];
    const float* Wv1 = (const float*)d_in[9];
    const float* bv1 = (const float*)d_in[10];
    const float* Wk2 = (const float*)d_in[11];
    const float* bk2 = (const float*)d_in[12];
    const float* Wv2 = (const float*)d_in[13];
    const float* bv2 = (const float*)d_in[14];
    const float* Wo  = (const float*)d_in[15];
    const float* bo  = (const float*)d_in[16];
    float* out = (float*)d_out;

    // Workspace layout (MB): Wot[0,2) xb[2,6) c1b[6,10) c2b[10,14) Wqt[14,15)
    // Wk1t[15,16) Wk2t[16,17) Wv1t[17,19) Wv2t[19,21) qbuf[21,23) kbuf[23,27)
    // vbT[27,35).  Post-proj overlaps (region [2,21) dead after proj_all):
    // Opart[2,18) mpk[18,18.5) ml[18.5,18.75) abuf[19,23) (over Wv2t+qbuf,
    // both dead before combine writes).
    char* W = (char*)d_ws;
    unsigned short* Wot  = (unsigned short*)(W);
    unsigned short* xb   = (unsigned short*)(W + (2ull  << 20));
    unsigned short* c1b  = (unsigned short*)(W + (6ull  << 20));
    unsigned short* c2b  = (unsigned short*)(W + (10ull << 20));
    unsigned short* Wqt  = (unsigned short*)(W + (14ull << 20));
    unsigned short* Wk1t = (unsigned short*)(W + (15ull << 20));
    unsigned short* Wk2t = (unsigned short*)(W + (16ull << 20));
    unsigned short* Wv1t = (unsigned short*)(W + (17ull << 20));
    unsigned short* Wv2t = (unsigned short*)(W + (19ull << 20));
    unsigned short* qbuf = (unsigned short*)(W + (21ull << 20));
    unsigned short* kbuf = (unsigned short*)(W + (23ull << 20));
    unsigned short* vbT  = (unsigned short*)(W + (27ull << 20));
    float*              Opart = (float*)(W + (2ull << 20));
    unsigned long long* mpk   = (unsigned long long*)(W + (18ull << 20));
    float*              mlb   = (float*)(W + (18ull << 20) + (1ull << 19));
    unsigned short*     abuf  = (unsigned short*)(W + (19ull << 20));

    cast3   <<<dim3(1024, 1, 3), 256, 0, stream>>>(x, context, context2, xb, c1b, c2b);
    cast_t3 <<<dim3(8, 16, 3),   256, 0, stream>>>(Wq, Wk1, Wk2, Wqt, Wk1t, Wk2t, 1024, 512);
    cast_t3 <<<dim3(16, 16, 3),  256, 0, stream>>>(Wv1, Wv2, Wo, Wv1t, Wv2t, Wot, 1024, 1024);
    proj_all<<<dim3(448),        256, 0, stream>>>(xb, c1b, c2b, Wqt, Wk1t, Wk2t, Wv1t, Wv2t,
                                                   bq, bk1, bk2, bv1, bv2, qbuf, kbuf, vbT);
    pack_mask<<<dim3(512),       256, 0, stream>>>(mask1, mask2, mpk);   // after proj: mpk overlaps Wv1t
    attn_mfma<<<dim3(512),       256, 0, stream>>>(qbuf, kbuf, vbT, mpk, Opart, mlb);
    attn_combine<<<dim3(2048),   256, 0, stream>>>(Opart, mlb, abuf);
    gemm_out<<<dim3(8, 16),      256, 0, stream>>>(abuf, Wot, bo, out);
}

// Round 4
// 240.174 us; speedup vs baseline: 3.4991x; 1.0699x over previous
//
#include <hip/hip_runtime.h>
#include <math.h>

typedef short bf16x8 __attribute__((ext_vector_type(8)));
typedef float f32x4  __attribute__((ext_vector_type(4)));

__device__ __forceinline__ unsigned short f2bf(float f) {
    unsigned int u = __builtin_bit_cast(unsigned int, f);
    u += 0x7FFFu + ((u >> 16) & 1u);
    return (unsigned short)(u >> 16);
}

// async global->LDS, 16B per lane. LDS dest = wave-uniform base + lane*16.
__device__ __forceinline__ void gld16(const unsigned short* g, unsigned short* l) {
    __builtin_amdgcn_global_load_lds(
        (const __attribute__((address_space(1))) void*)g,
        (__attribute__((address_space(3))) void*)l, 16, 0, 0);
}

// ---------------------------------------------------------------------------
// Cast 3 activation tensors fp32 -> bf16 (row-major)
// ---------------------------------------------------------------------------
__global__ __launch_bounds__(256) void cast3(
    const float* __restrict__ a0, const float* __restrict__ a1, const float* __restrict__ a2,
    unsigned short* __restrict__ o0, unsigned short* __restrict__ o1, unsigned short* __restrict__ o2)
{
    const int z = blockIdx.z;
    const float* a = z == 0 ? a0 : (z == 1 ? a1 : a2);
    unsigned short* o = z == 0 ? o0 : (z == 1 ? o1 : o2);
    size_t i = ((size_t)blockIdx.x * 256 + threadIdx.x) * 8;
    float4 x0 = *(const float4*)&a[i];
    float4 x1 = *(const float4*)&a[i + 4];
    uint4 pk;
    pk.x = (unsigned)f2bf(x0.x) | ((unsigned)f2bf(x0.y) << 16);
    pk.y = (unsigned)f2bf(x0.z) | ((unsigned)f2bf(x0.w) << 16);
    pk.z = (unsigned)f2bf(x1.x) | ((unsigned)f2bf(x1.y) << 16);
    pk.w = (unsigned)f2bf(x1.z) | ((unsigned)f2bf(x1.w) << 16);
    *(uint4*)&o[i] = pk;
}

// ---------------------------------------------------------------------------
// Cast+transpose 3 weights: W[K][N] fp32 -> Wt[N][K] bf16
// ---------------------------------------------------------------------------
__global__ __launch_bounds__(256) void cast_t3(
    const float* __restrict__ W0, const float* __restrict__ W1, const float* __restrict__ W2,
    unsigned short* __restrict__ T0, unsigned short* __restrict__ T1, unsigned short* __restrict__ T2,
    int K, int N)
{
    __shared__ float T[64][65];
    const int z = blockIdx.z;
    const float* W = z == 0 ? W0 : (z == 1 ? W1 : W2);
    unsigned short* O = z == 0 ? T0 : (z == 1 ? T1 : T2);
    const int n0 = blockIdx.x << 6, k0 = blockIdx.y << 6;
    const int t = threadIdx.x;
    #pragma unroll
    for (int i = 0; i < 4; i++) {
        int vi = t + (i << 8);
        int r = vi >> 4, c4 = (vi & 15) << 2;
        *(float4*)&T[r][c4] = *(const float4*)&W[(size_t)(k0 + r) * N + n0 + c4];
    }
    __syncthreads();
    #pragma unroll
    for (int i = 0; i < 4; i++) {
        int vi = t + (i << 8);
        int n = vi >> 4, k4 = (vi & 15) << 2;
        uint2 pk;
        pk.x = (unsigned)f2bf(T[k4 + 0][n]) | ((unsigned)f2bf(T[k4 + 1][n]) << 16);
        pk.y = (unsigned)f2bf(T[k4 + 2][n]) | ((unsigned)f2bf(T[k4 + 3][n]) << 16);
        *(uint2*)&O[(size_t)(n0 + n) * K + k0 + k4] = pk;
    }
}

// ---------------------------------------------------------------------------
// Pack masks to bits: mpk[b*1024+q][32] uint64; word w covers j=64w..64w+63
// ---------------------------------------------------------------------------
__global__ __launch_bounds__(256) void pack_mask(
    const int* __restrict__ mask1, const int* __restrict__ mask2,
    unsigned long long* __restrict__ mpk)
{
    int wid = (blockIdx.x << 2) + (threadIdx.x >> 6);   // row 0..2047
    int lane = threadIdx.x & 63;
    const int* m1 = mask1 + ((size_t)wid << 10);
    const int* m2 = mask2 + ((size_t)wid << 10);
    unsigned long long* o = mpk + ((size_t)wid << 5);
    #pragma unroll
    for (int win = 0; win < 16; win++) {
        unsigned long long bal = __ballot(m1[(win << 6) + lane] != 0);
        if (lane == 0) o[win] = bal;
    }
    #pragma unroll
    for (int win = 0; win < 16; win++) {
        unsigned long long bal = __ballot(m2[(win << 6) + lane] != 0);
        if (lane == 0) o[16 + win] = bal;
    }
}

// ---------------------------------------------------------------------------
// m97-style MFMA GEMM core, templated on N-tile (64 or 128). M-tile 128, BK=32.
// ---------------------------------------------------------------------------
template<int NT>
__device__ __forceinline__ void gemm_core(
    const unsigned short* __restrict__ A,
    const unsigned short* __restrict__ Wt,
    int K, int gm0, int gn0,
    unsigned short (*As)[32], unsigned short (*Bs)[32],
    f32x4 (&acc)[4][NT / 32])
{
    constexpr int NS = NT / 32;
    const int t = threadIdx.x;
    const int lane = t & 63, w = t >> 6;
    const int wm = (w & 1) << 6, wn = (w >> 1) * (NT / 2);
    const int l15 = lane & 15, quad = lane >> 4;

    for (int k0 = 0; k0 < K; k0 += 32) {
        __syncthreads();
        #pragma unroll
        for (int i = 0; i < 2; i++) {
            int r0 = (i << 6) + (w << 4);
            int ra = r0 + (lane >> 2);
            int kc = (lane & 3) << 3;
            gld16(&A[(size_t)(gm0 + ra) * K + k0 + kc], &As[r0][0] + ((size_t)lane << 3));
        }
        #pragma unroll
        for (int i = 0; i < NT / 64; i++) {
            int r0 = (i << 6) + (w << 4);
            int ra = r0 + (lane >> 2);
            int kc = (lane & 3) << 3;
            gld16(&Wt[(size_t)(gn0 + ra) * K + k0 + kc], &Bs[r0][0] + ((size_t)lane << 3));
        }
        __syncthreads();
        bf16x8 af[4], bg[NS];
        #pragma unroll
        for (int i = 0; i < 4; i++)
            af[i] = *(const bf16x8*)&As[wm + (i << 4) + l15][quad << 3];
        #pragma unroll
        for (int j = 0; j < NS; j++)
            bg[j] = *(const bf16x8*)&Bs[wn + (j << 4) + l15][quad << 3];
        #pragma unroll
        for (int i = 0; i < 4; i++)
            #pragma unroll
            for (int j = 0; j < NS; j++)
                acc[i][j] = __builtin_amdgcn_mfma_f32_16x16x32_bf16(af[i], bg[j], acc[i][j], 0, 0, 0);
    }
}

// ---------------------------------------------------------------------------
// All 5 projections in one launch. 448 blocks, tiles 128x128.
// ---------------------------------------------------------------------------
__global__ __launch_bounds__(256) void proj_all(
    const unsigned short* __restrict__ xb, const unsigned short* __restrict__ c1b,
    const unsigned short* __restrict__ c2b,
    const unsigned short* __restrict__ Wqt, const unsigned short* __restrict__ Wk1t,
    const unsigned short* __restrict__ Wk2t, const unsigned short* __restrict__ Wv1t,
    const unsigned short* __restrict__ Wv2t,
    const float* __restrict__ bq, const float* __restrict__ bk1, const float* __restrict__ bk2,
    const float* __restrict__ bv1, const float* __restrict__ bv2,
    unsigned short* __restrict__ qbuf, unsigned short* __restrict__ kbuf,
    unsigned short* __restrict__ vbT)
{
    __shared__ unsigned short As[128][32];
    __shared__ unsigned short Bs[128][32];
    const int bid = blockIdx.x;
    int z, bx, by;
    if (bid < 192) { z = bid >> 6; int l = bid & 63; by = l >> 2; bx = l & 3; }
    else { int l = bid - 192; z = 3 + (l >> 7); l &= 127; by = l >> 3; bx = l & 7; }
    const unsigned short* A  = (z == 0) ? xb : (z == 1 || z == 3) ? c1b : c2b;
    const unsigned short* Wt = (z == 0) ? Wqt : (z == 1) ? Wk1t : (z == 2) ? Wk2t
                             : (z == 3) ? Wv1t : Wv2t;
    const float* bias = (z == 0) ? bq : (z == 1) ? bk1 : (z == 2) ? bk2
                      : (z == 3) ? bv1 : bv2;
    const int gm0 = by << 7, gn0 = bx << 7;

    f32x4 acc[4][4];
    #pragma unroll
    for (int i = 0; i < 4; i++)
        #pragma unroll
        for (int j = 0; j < 4; j++) acc[i][j] = (f32x4){0.f, 0.f, 0.f, 0.f};

    gemm_core<128>(A, Wt, 1024, gm0, gn0, As, Bs, acc);

    const int lane = threadIdx.x & 63, w = threadIdx.x >> 6;
    const int wm = (w & 1) << 6, wn = (w >> 1) << 6;
    const int l15 = lane & 15, quad = lane >> 4;
    float bb[4];
    #pragma unroll
    for (int j = 0; j < 4; j++) bb[j] = bias[gn0 + wn + (j << 4) + l15];

    if (z < 3) {
        unsigned short* out = (z == 0) ? qbuf : kbuf;
        const int obs = (z == 0) ? 1024 : 2048;
        const int off = (z == 2) ? 1024 : 0;
        #pragma unroll
        for (int i = 0; i < 4; i++) {
            int mb = gm0 + wm + (i << 4) + (quad << 2);
            #pragma unroll
            for (int p = 0; p < 4; p++) {
                int m = mb + p;
                int orow = ((m >> 10) * obs) + off + (m & 1023);
                #pragma unroll
                for (int j = 0; j < 4; j++)
                    out[(size_t)orow * 512 + gn0 + wn + (j << 4) + l15] = f2bf(acc[i][j][p] + bb[j]);
            }
        }
    } else {
        const int off = (z == 3) ? 0 : 1024;
        #pragma unroll
        for (int i = 0; i < 4; i++) {
            int mb = gm0 + wm + (i << 4) + (quad << 2);
            int b = mb >> 10;
            int jj = (mb & 1023) + off;
            #pragma unroll
            for (int j = 0; j < 4; j++) {
                int n = gn0 + wn + (j << 4) + l15;
                unsigned long long pk = 0;
                #pragma unroll
                for (int p = 0; p < 4; p++)
                    pk |= (unsigned long long)f2bf(acc[i][j][p] + bb[j]) << (16 * p);
                *(unsigned long long*)&vbT[((size_t)b * 1024 + n) * 2048 + jj] = pk;
            }
        }
    }
}

// ---------------------------------------------------------------------------
// final: out = abuf(bf16) @ Wot^T + bo, fp32 out. N-tile 64 -> 256 blocks.
// ---------------------------------------------------------------------------
__global__ __launch_bounds__(256) void gemm_out(
    const unsigned short* __restrict__ abuf, const unsigned short* __restrict__ Wot,
    const float* __restrict__ bo, float* __restrict__ out)
{
    __shared__ unsigned short As[128][32];
    __shared__ unsigned short Bs[64][32];
    const int gm0 = blockIdx.y << 7, gn0 = blockIdx.x << 6;

    f32x4 acc[4][2];
    #pragma unroll
    for (int i = 0; i < 4; i++)
        #pragma unroll
        for (int j = 0; j < 2; j++) acc[i][j] = (f32x4){0.f, 0.f, 0.f, 0.f};

    gemm_core<64>(abuf, Wot, 1024, gm0, gn0, As, Bs, acc);

    const int lane = threadIdx.x & 63, w = threadIdx.x >> 6;
    const int wm = (w & 1) << 6, wn = (w >> 1) << 5;
    const int l15 = lane & 15, quad = lane >> 4;
    float bb[2];
    #pragma unroll
    for (int j = 0; j < 2; j++) bb[j] = bo[gn0 + wn + (j << 4) + l15];
    #pragma unroll
    for (int i = 0; i < 4; i++) {
        int mb = gm0 + wm + (i << 4) + (quad << 2);
        #pragma unroll
        for (int p = 0; p < 4; p++)
            #pragma unroll
            for (int j = 0; j < 2; j++)
                out[(size_t)(mb + p) * 1024 + gn0 + wn + (j << 4) + l15] = acc[i][j][p] + bb[j];
    }
}

// ---------------------------------------------------------------------------
// MFMA flash attention, S^T-softmax formulation. Block=(hs,b,h,64 q), 512 blks.
// S^T = K Q^T: C-layout col=q, row=j => each lane owns ONE q-row, 32 j-values
// in registers. Softmax: in-register reduce + 2 shfl_xor (quads). P packs to
// 8 ds_write_b64. Alpha transposes to PV row-domain via 4 bpermutes.
// ---------------------------------------------------------------------------
__global__ __launch_bounds__(256) void attn_mfma(
    const unsigned short* __restrict__ qbuf, const unsigned short* __restrict__ kbuf,
    const unsigned short* __restrict__ vbT, const unsigned long long* __restrict__ mpk,
    float* __restrict__ Opart, float* __restrict__ ml)
{
    __shared__ unsigned short Ks[128][64];    // [j][d]   xor-swizzled chunks
    __shared__ unsigned short VsT[128][128];  // [feat][j] xor-swizzled chunks
    __shared__ unsigned short Ps[64][132];    // [q][j]   padded (2-way = free)

    const int t = threadIdx.x;
    const int bid = blockIdx.x;
    const int hs = bid >> 8, r = bid & 255;
    const int h = r & 7, qt = (r >> 3) & 15, b = r >> 7;
    const int q0 = qt << 6;
    const int lane = t & 63, w = t >> 6, l15 = lane & 15, quad = lane >> 4;

    // Q B-frags (loop-invariant): lane l15 = q, quad*8 = d
    const unsigned short* qrow = qbuf + (((size_t)(b << 10) + q0 + (w << 4) + l15) << 9) + (h << 6);
    const bf16x8 aq0 = *(const bf16x8*)&qrow[quad << 3];
    const bf16x8 aq1 = *(const bf16x8*)&qrow[32 + (quad << 3)];

    f32x4 acc[8];
    #pragma unroll
    for (int ct = 0; ct < 8; ct++) acc[ct] = (f32x4){0.f, 0.f, 0.f, 0.f};
    float m_l = -3.0e38f, l_l = 0.f;          // per-lane state for q = l15-row

    const size_t kbase = (size_t)b << 20;
    const size_t vbase = ((size_t)((b << 10) + (h << 7))) << 11;
    const unsigned long long* mrow = mpk + (((size_t)(b << 10) + q0 + (w << 4) + l15) << 5);

    for (int jt = 0; jt < 8; jt++) {
        const int j0 = (hs << 10) + (jt << 7);
        __syncthreads();
        #pragma unroll
        for (int i = 0; i < 4; i++) {             // K: 128 x 64
            int vi = t + (i << 8);
            int row = vi >> 3, c = vi & 7;
            *(uint4*)&Ks[row][(c ^ (row & 7)) << 3] =
                *(const uint4*)&kbuf[kbase + ((size_t)(j0 + row) << 9) + (h << 6) + (c << 3)];
        }
        #pragma unroll
        for (int i = 0; i < 8; i++) {             // V^T: 128 feat x 128 j
            int vi = t + (i << 8);
            int f = vi >> 4, c = vi & 15;
            int sc = (c & 8) | ((c & 7) ^ (f & 7));
            *(uint4*)&VsT[f][sc << 3] =
                *(const uint4*)&vbT[vbase + ((size_t)f << 11) + j0 + (c << 3)];
        }
        __syncthreads();

        // S^T = K Q^T : 8 j-subtiles x 16 q. Lane: col=q=l15, row j=n*16+quad*4+p
        f32x4 s[8];
        #pragma unroll
        for (int n = 0; n < 8; n++) {
            int rowk = (n << 4) + l15;
            bf16x8 bk0 = *(const bf16x8*)&Ks[rowk][(quad ^ (l15 & 7)) << 3];
            bf16x8 bk1 = *(const bf16x8*)&Ks[rowk][((quad | 4) ^ (l15 & 7)) << 3];
            s[n] = (f32x4){0.f, 0.f, 0.f, 0.f};
            s[n] = __builtin_amdgcn_mfma_f32_16x16x32_bf16(bk0, aq0, s[n], 0, 0, 0);
            s[n] = __builtin_amdgcn_mfma_f32_16x16x32_bf16(bk1, aq1, s[n], 0, 0, 0);
        }

        // scale + mask: 2 u64 words cover this lane's q-row for j0..j0+127
        const int wbase = j0 >> 6;
        const unsigned long long w0 = mrow[wbase], w1 = mrow[wbase + 1];
        #pragma unroll
        for (int n = 0; n < 8; n++) {
            unsigned long long wd = (n < 4) ? w0 : w1;
            int bit0 = ((n & 3) << 4) + (quad << 2);
            #pragma unroll
            for (int p = 0; p < 4; p++) {
                float sv = s[n][p] * 0.125f;
                s[n][p] = ((wd >> (bit0 + p)) & 1ull) ? sv : -3.0e38f;
            }
        }

        // softmax for q=l15 row: in-register reduce + 2 shfl (across quads)
        float mt = s[0][0];
        #pragma unroll
        for (int n = 0; n < 8; n++)
            #pragma unroll
            for (int p = 0; p < 4; p++) mt = fmaxf(mt, s[n][p]);
        mt = fmaxf(mt, __shfl_xor(mt, 16, 64));
        mt = fmaxf(mt, __shfl_xor(mt, 32, 64));
        float mn = fmaxf(m_l, mt);
        float ls = 0.f;
        #pragma unroll
        for (int n = 0; n < 8; n++) {
            float e0 = __expf(s[n][0] - mn), e1 = __expf(s[n][1] - mn);
            float e2 = __expf(s[n][2] - mn), e3 = __expf(s[n][3] - mn);
            ls += (e0 + e1) + (e2 + e3);
            unsigned long long pk = (unsigned long long)f2bf(e0)
                | ((unsigned long long)f2bf(e1) << 16)
                | ((unsigned long long)f2bf(e2) << 32)
                | ((unsigned long long)f2bf(e3) << 48);
            *(unsigned long long*)&Ps[(w << 4) + l15][(n << 4) + (quad << 2)] = pk;
        }
        ls += __shfl_xor(ls, 16, 64);
        ls += __shfl_xor(ls, 32, 64);
        float al = __expf(m_l - mn);
        l_l = l_l * al + ls;
        m_l = mn;

        // alpha -> PV accumulator row-domain (row q = quad*4+p): src l15' = quad*4+p
        float ar[4];
        #pragma unroll
        for (int p = 0; p < 4; p++)
            ar[p] = __shfl(al, (lane & 48) | ((quad << 2) + p), 64);
        #pragma unroll
        for (int ct = 0; ct < 8; ct++)
            #pragma unroll
            for (int p = 0; p < 4; p++) acc[ct][p] *= ar[p];

        // O += P V : A-frags from Ps (intra-wave RAW), B-frags from VsT
        bf16x8 ap[4];
        #pragma unroll
        for (int win = 0; win < 4; win++)
            ap[win] = *(const bf16x8*)&Ps[(w << 4) + l15][(win << 5) + (quad << 3)];
        #pragma unroll
        for (int ct = 0; ct < 8; ct++) {
            int fv = (ct << 4) + l15;
            #pragma unroll
            for (int win = 0; win < 4; win++) {
                int c = (win << 2) + quad;
                int sc = (c & 8) | ((c & 7) ^ (l15 & 7));
                bf16x8 bv = *(const bf16x8*)&VsT[fv][sc << 3];
                acc[ct] = __builtin_amdgcn_mfma_f32_16x16x32_bf16(ap[win], bv, acc[ct], 0, 0, 0);
            }
        }
    }

    #pragma unroll
    for (int p = 0; p < 4; p++) {
        int q = q0 + (w << 4) + (quad << 2) + p;
        size_t idx = (size_t)(hs << 14) + (b << 13) + (h << 10) + q;
        #pragma unroll
        for (int ct = 0; ct < 8; ct++)
            Opart[(idx << 7) + (ct << 4) + l15] = acc[ct][p];
    }
    if (quad == 0) {
        int q = q0 + (w << 4) + l15;
        size_t idx = (size_t)(hs << 14) + (b << 13) + (h << 10) + q;
        ml[(idx << 1) + 0] = m_l;
        ml[(idx << 1) + 1] = l_l;
    }
}

// ---------------------------------------------------------------------------
// Combine the two j-halves -> abuf bf16
// ---------------------------------------------------------------------------
__global__ __launch_bounds__(256) void attn_combine(
    const float* __restrict__ Opart, const float* __restrict__ ml,
    unsigned short* __restrict__ abuf)
{
    int id = (blockIdx.x << 8) + threadIdx.x;       // 524288
    int bhq = id >> 5, c4 = (id & 31) << 2;
    float2 ml0 = ((const float2*)ml)[bhq];
    float2 ml1 = ((const float2*)ml)[16384 + bhq];
    float M = fmaxf(ml0.x, ml1.x);
    float a0 = __expf(ml0.x - M), a1 = __expf(ml1.x - M);
    float inv = 1.0f / (ml0.y * a0 + ml1.y * a1);
    float4 o0 = *(const float4*)&Opart[((size_t)bhq << 7) + c4];
    float4 o1 = *(const float4*)&Opart[((size_t)(16384 + bhq) << 7) + c4];
    int b = bhq >> 13, hh = (bhq >> 10) & 7, q = bhq & 1023;
    float r0 = (o0.x * a0 + o1.x * a1) * inv;
    float r1 = (o0.y * a0 + o1.y * a1) * inv;
    float r2 = (o0.z * a0 + o1.z * a1) * inv;
    float r3 = (o0.w * a0 + o1.w * a1) * inv;
    unsigned long long pk = (unsigned long long)f2bf(r0)
        | ((unsigned long long)f2bf(r1) << 16)
        | ((unsigned long long)f2bf(r2) << 32)
        | ((unsigned long long)f2bf(r3) << 48);
    *(unsigned long long*)&abuf[((size_t)((b << 10) + q) << 10) + (hh << 7) + c4] = pk;
}

// ---------------------------------------------------------------------------
extern "C" void kernel_launch(void* const* d_in, const int* in_sizes, int n_in,
                              void* d_out, int out_size, void* d_ws, size_t ws_size,
                              hipStream_t stream)
{
    const float* x        = (const float*)d_in[0];
    const float* context  = (const float*)d_in[1];
    const float* context2 = (const float*)d_in[2];
    const int*   mask1    = (const int*)d_in[3];
    const int*   mask2    = (const int*)d_in[4];
    const float* Wq  = (const float*)d_in[5];
    const float* bq  = (const float*)d_in[6];
    const float* Wk1 = (const float*)d_in[7];
    const float* bk1 = (const float*)d_in[8];
    const float* Wv1 = (const float*)d_in[9];
    const float* bv1 = (const float*)d_in[10];
    const float* Wk2 = (const float*)d_in[11];
    const float* bk2 = (const float*)d_in[12];
    const float* Wv2 = (const float*)d_in[13];
    const float* bv2 = (const float*)d_in[14];
    const float* Wo  = (const float*)d_in[15];
    const float* bo  = (const float*)d_in[16];
    float* out = (float*)d_out;

    // Workspace layout (MB): Wot[0,2) xb[2,6) c1b[6,10) c2b[10,14) Wqt[14,15)
    // Wk1t[15,16) Wk2t[16,17) Wv1t[17,19) Wv2t[19,21) qbuf[21,23) kbuf[23,27)
    // vbT[27,35).  Post-proj overlaps (region [2,21) dead after proj_all):
    // Opart[2,18) mpk[18,18.5) ml[18.5,18.75) abuf[19,23).
    char* W = (char*)d_ws;
    unsigned short* Wot  = (unsigned short*)(W);
    unsigned short* xb   = (unsigned short*)(W + (2ull  << 20));
    unsigned short* c1b  = (unsigned short*)(W + (6ull  << 20));
    unsigned short* c2b  = (unsigned short*)(W + (10ull << 20));
    unsigned short* Wqt  = (unsigned short*)(W + (14ull << 20));
    unsigned short* Wk1t = (unsigned short*)(W + (15ull << 20));
    unsigned short* Wk2t = (unsigned short*)(W + (16ull << 20));
    unsigned short* Wv1t = (unsigned short*)(W + (17ull << 20));
    unsigned short* Wv2t = (unsigned short*)(W + (19ull << 20));
    unsigned short* qbuf = (unsigned short*)(W + (21ull << 20));
    unsigned short* kbuf = (unsigned short*)(W + (23ull << 20));
    unsigned short* vbT  = (unsigned short*)(W + (27ull << 20));
    float*              Opart = (float*)(W + (2ull << 20));
    unsigned long long* mpk   = (unsigned long long*)(W + (18ull << 20));
    float*              mlb   = (float*)(W + (18ull << 20) + (1ull << 19));
    unsigned short*     abuf  = (unsigned short*)(W + (19ull << 20));

    cast3   <<<dim3(1024, 1, 3), 256, 0, stream>>>(x, context, context2, xb, c1b, c2b);
    cast_t3 <<<dim3(8, 16, 3),   256, 0, stream>>>(Wq, Wk1, Wk2, Wqt, Wk1t, Wk2t, 1024, 512);
    cast_t3 <<<dim3(16, 16, 3),  256, 0, stream>>>(Wv1, Wv2, Wo, Wv1t, Wv2t, Wot, 1024, 1024);
    proj_all<<<dim3(448),        256, 0, stream>>>(xb, c1b, c2b, Wqt, Wk1t, Wk2t, Wv1t, Wv2t,
                                                   bq, bk1, bk2, bv1, bv2, qbuf, kbuf, vbT);
    pack_mask<<<dim3(512),       256, 0, stream>>>(mask1, mask2, mpk);
    attn_mfma<<<dim3(512),       256, 0, stream>>>(qbuf, kbuf, vbT, mpk, Opart, mlb);
    attn_combine<<<dim3(2048),   256, 0, stream>>>(Opart, mlb, abuf);
    gemm_out<<<dim3(16, 16),     256, 0, stream>>>(abuf, Wot, bo, out);
}

// Round 5
// 217.961 us; speedup vs baseline: 3.8557x; 1.1019x over previous
//
#include <hip/hip_runtime.h>
#include <math.h>

typedef short bf16x8 __attribute__((ext_vector_type(8)));
typedef float f32x4  __attribute__((ext_vector_type(4)));

__device__ __forceinline__ unsigned short f2bf(float f) {
    unsigned int u = __builtin_bit_cast(unsigned int, f);
    u += 0x7FFFu + ((u >> 16) & 1u);
    return (unsigned short)(u >> 16);
}
__device__ __forceinline__ float bf2f(unsigned short u) {
    return __builtin_bit_cast(float, (unsigned int)u << 16);
}

// async global->LDS, 16B per lane. LDS dest = wave-uniform base + lane*16.
__device__ __forceinline__ void gld16(const unsigned short* g, unsigned short* l) {
    __builtin_amdgcn_global_load_lds(
        (const __attribute__((address_space(1))) void*)g,
        (__attribute__((address_space(3))) void*)l, 16, 0, 0);
}

// ---------------------------------------------------------------------------
// prep: fused cast3 + weight transposes (+Wo column permute) + mask pack.
// grid 4736: [0,3072)=cast3, [3072,3456)=Wq/Wk1/Wk2 T, [3456,4224)=Wv1/Wv2/Wo T,
// [4224,4736)=pack_mask.
// ---------------------------------------------------------------------------
__global__ __launch_bounds__(256) void prep(
    const float* __restrict__ x, const float* __restrict__ c1, const float* __restrict__ c2,
    const int* __restrict__ mask1, const int* __restrict__ mask2,
    const float* __restrict__ Wq, const float* __restrict__ Wk1, const float* __restrict__ Wk2,
    const float* __restrict__ Wv1, const float* __restrict__ Wv2, const float* __restrict__ Wo,
    unsigned short* __restrict__ xb, unsigned short* __restrict__ c1b, unsigned short* __restrict__ c2b,
    unsigned short* __restrict__ Wqt, unsigned short* __restrict__ Wk1t, unsigned short* __restrict__ Wk2t,
    unsigned short* __restrict__ Wv1t, unsigned short* __restrict__ Wv2t, unsigned short* __restrict__ Wot,
    unsigned long long* __restrict__ mpk)
{
    __shared__ float T[64][65];
    const int bid = blockIdx.x, t = threadIdx.x;

    if (bid < 3072) {                                   // cast fp32->bf16
        const int z = bid >> 10;
        const float* a = z == 0 ? x : (z == 1 ? c1 : c2);
        unsigned short* o = z == 0 ? xb : (z == 1 ? c1b : c2b);
        size_t i = ((size_t)(bid & 1023) * 256 + t) * 8;
        float4 x0 = *(const float4*)&a[i];
        float4 x1 = *(const float4*)&a[i + 4];
        uint4 pk;
        pk.x = (unsigned)f2bf(x0.x) | ((unsigned)f2bf(x0.y) << 16);
        pk.y = (unsigned)f2bf(x0.z) | ((unsigned)f2bf(x0.w) << 16);
        pk.z = (unsigned)f2bf(x1.x) | ((unsigned)f2bf(x1.y) << 16);
        pk.w = (unsigned)f2bf(x1.z) | ((unsigned)f2bf(x1.w) << 16);
        *(uint4*)&o[i] = pk;
        return;
    }
    if (bid < 4224) {                                   // weight cast+transpose
        const float* W; unsigned short* O; int N, n0, k0; bool perm = false;
        if (bid < 3456) {
            int l = bid - 3072, z = l >> 7, rem = l & 127;
            W = z == 0 ? Wq : (z == 1 ? Wk1 : Wk2);
            O = z == 0 ? Wqt : (z == 1 ? Wk1t : Wk2t);
            N = 512; n0 = (rem & 7) << 6; k0 = (rem >> 3) << 6;
        } else {
            int l = bid - 3456, z = l >> 8, rem = l & 255;
            W = z == 0 ? Wv1 : (z == 1 ? Wv2 : Wo);
            O = z == 0 ? Wv1t : (z == 1 ? Wv2t : Wot);
            N = 1024; n0 = (rem & 15) << 6; k0 = (rem >> 4) << 6;
            perm = (z == 2);
        }
        #pragma unroll
        for (int i = 0; i < 4; i++) {
            int vi = t + (i << 8);
            int r = vi >> 4, c4 = (vi & 15) << 2;
            *(float4*)&T[r][c4] = *(const float4*)&W[(size_t)(k0 + r) * N + n0 + c4];
        }
        __syncthreads();
        #pragma unroll
        for (int i = 0; i < 4; i++) {
            int vi = t + (i << 8);
            int n = vi >> 4, k4 = (vi & 15) << 2;
            if (!perm) {
                uint2 pk;
                pk.x = (unsigned)f2bf(T[k4 + 0][n]) | ((unsigned)f2bf(T[k4 + 1][n]) << 16);
                pk.y = (unsigned)f2bf(T[k4 + 2][n]) | ((unsigned)f2bf(T[k4 + 3][n]) << 16);
                *(uint2*)&O[(size_t)(n0 + n) * 1024 + k0 + k4] = pk;
            } else {
                #pragma unroll
                for (int ii = 0; ii < 4; ii++) {
                    int k = k0 + k4 + ii, f = k & 127;
                    int kp = (k & ~127) | ((f & 15) << 3) | (f >> 4);   // head f-permute
                    O[(size_t)(n0 + n) * 1024 + kp] = f2bf(T[k4 + ii][n]);
                }
            }
        }
        return;
    }
    {                                                   // mask pack
        int wid = ((bid - 4224) << 2) + (t >> 6);
        int lane = t & 63;
        const int* m1 = mask1 + ((size_t)wid << 10);
        const int* m2 = mask2 + ((size_t)wid << 10);
        unsigned long long* o = mpk + ((size_t)wid << 5);
        #pragma unroll
        for (int win = 0; win < 16; win++) {
            unsigned long long bal = __ballot(m1[(win << 6) + lane] != 0);
            if (lane == 0) o[win] = bal;
        }
        #pragma unroll
        for (int win = 0; win < 16; win++) {
            unsigned long long bal = __ballot(m2[(win << 6) + lane] != 0);
            if (lane == 0) o[16 + win] = bal;
        }
    }
}

// ---------------------------------------------------------------------------
// m97-style MFMA GEMM core, templated on N-tile (64 or 128). M-tile 128, BK=32.
// ---------------------------------------------------------------------------
template<int NT>
__device__ __forceinline__ void gemm_core(
    const unsigned short* __restrict__ A,
    const unsigned short* __restrict__ Wt,
    int K, int gm0, int gn0,
    unsigned short (*As)[32], unsigned short (*Bs)[32],
    f32x4 (&acc)[4][NT / 32])
{
    constexpr int NS = NT / 32;
    const int t = threadIdx.x;
    const int lane = t & 63, w = t >> 6;
    const int wm = (w & 1) << 6, wn = (w >> 1) * (NT / 2);
    const int l15 = lane & 15, quad = lane >> 4;

    for (int k0 = 0; k0 < K; k0 += 32) {
        __syncthreads();
        #pragma unroll
        for (int i = 0; i < 2; i++) {
            int r0 = (i << 6) + (w << 4);
            int ra = r0 + (lane >> 2);
            int kc = (lane & 3) << 3;
            gld16(&A[(size_t)(gm0 + ra) * K + k0 + kc], &As[r0][0] + ((size_t)lane << 3));
        }
        #pragma unroll
        for (int i = 0; i < NT / 64; i++) {
            int r0 = (i << 6) + (w << 4);
            int ra = r0 + (lane >> 2);
            int kc = (lane & 3) << 3;
            gld16(&Wt[(size_t)(gn0 + ra) * K + k0 + kc], &Bs[r0][0] + ((size_t)lane << 3));
        }
        __syncthreads();
        bf16x8 af[4], bg[NS];
        #pragma unroll
        for (int i = 0; i < 4; i++)
            af[i] = *(const bf16x8*)&As[wm + (i << 4) + l15][quad << 3];
        #pragma unroll
        for (int j = 0; j < NS; j++)
            bg[j] = *(const bf16x8*)&Bs[wn + (j << 4) + l15][quad << 3];
        #pragma unroll
        for (int i = 0; i < 4; i++)
            #pragma unroll
            for (int j = 0; j < NS; j++)
                acc[i][j] = __builtin_amdgcn_mfma_f32_16x16x32_bf16(af[i], bg[j], acc[i][j], 0, 0, 0);
    }
}

// ---------------------------------------------------------------------------
// All 5 projections. Outputs: qbuf [2048][512] rm; khb[b][h][j][64] (d-chunk
// swizzled by j&7); vhb[b][h][f][2048] (j-chunk-in-64-window swizzled by f&7).
// ---------------------------------------------------------------------------
__global__ __launch_bounds__(256) void proj_all(
    const unsigned short* __restrict__ xb, const unsigned short* __restrict__ c1b,
    const unsigned short* __restrict__ c2b,
    const unsigned short* __restrict__ Wqt, const unsigned short* __restrict__ Wk1t,
    const unsigned short* __restrict__ Wk2t, const unsigned short* __restrict__ Wv1t,
    const unsigned short* __restrict__ Wv2t,
    const float* __restrict__ bq, const float* __restrict__ bk1, const float* __restrict__ bk2,
    const float* __restrict__ bv1, const float* __restrict__ bv2,
    unsigned short* __restrict__ qbuf, unsigned short* __restrict__ khb,
    unsigned short* __restrict__ vhb)
{
    __shared__ unsigned short As[128][32];
    __shared__ unsigned short Bs[128][32];
    const int bid = blockIdx.x;
    int z, bx, by;
    if (bid < 192) { z = bid >> 6; int l = bid & 63; by = l >> 2; bx = l & 3; }
    else { int l = bid - 192; z = 3 + (l >> 7); l &= 127; by = l >> 3; bx = l & 7; }
    const unsigned short* A  = (z == 0) ? xb : (z == 1 || z == 3) ? c1b : c2b;
    const unsigned short* Wt = (z == 0) ? Wqt : (z == 1) ? Wk1t : (z == 2) ? Wk2t
                             : (z == 3) ? Wv1t : Wv2t;
    const float* bias = (z == 0) ? bq : (z == 1) ? bk1 : (z == 2) ? bk2
                      : (z == 3) ? bv1 : bv2;
    const int gm0 = by << 7, gn0 = bx << 7;

    f32x4 acc[4][4];
    #pragma unroll
    for (int i = 0; i < 4; i++)
        #pragma unroll
        for (int j = 0; j < 4; j++) acc[i][j] = (f32x4){0.f, 0.f, 0.f, 0.f};

    gemm_core<128>(A, Wt, 1024, gm0, gn0, As, Bs, acc);

    const int lane = threadIdx.x & 63, w = threadIdx.x >> 6;
    const int wm = (w & 1) << 6, wn = (w >> 1) << 6;
    const int l15 = lane & 15, quad = lane >> 4;
    float bb[4];
    #pragma unroll
    for (int j = 0; j < 4; j++) bb[j] = bias[gn0 + wn + (j << 4) + l15];

    if (z == 0) {                                       // q: row-major
        #pragma unroll
        for (int i = 0; i < 4; i++) {
            int mb = gm0 + wm + (i << 4) + (quad << 2);
            #pragma unroll
            for (int p = 0; p < 4; p++)
                #pragma unroll
                for (int j = 0; j < 4; j++)
                    qbuf[(size_t)(mb + p) * 512 + gn0 + wn + (j << 4) + l15] = f2bf(acc[i][j][p] + bb[j]);
        }
    } else if (z < 3) {                                 // k: per-head swizzled
        const int off = (z == 2) ? 1024 : 0;
        #pragma unroll
        for (int i = 0; i < 4; i++) {
            int mb = gm0 + wm + (i << 4) + (quad << 2);
            int b = mb >> 10;
            #pragma unroll
            for (int j = 0; j < 4; j++) {
                int n = gn0 + wn + (j << 4) + l15;
                int hh = n >> 6, d = n & 63;
                size_t hb = ((size_t)((b << 3) + hh) << 17);
                #pragma unroll
                for (int p = 0; p < 4; p++) {
                    int jrow = off + ((mb + p) & 1023);
                    khb[hb + ((size_t)jrow << 6) + ((((d >> 3) ^ (jrow & 7))) << 3) + (d & 7)]
                        = f2bf(acc[i][j][p] + bb[j]);
                }
            }
        }
    } else {                                            // v: [b][h][f][j] swizzled
        const int off = (z == 3) ? 0 : 1024;
        #pragma unroll
        for (int i = 0; i < 4; i++) {
            int mb = gm0 + wm + (i << 4) + (quad << 2);
            int b = mb >> 10;
            int jj = (mb & 1023) + off;
            #pragma unroll
            for (int j = 0; j < 4; j++) {
                int n = gn0 + wn + (j << 4) + l15;
                int hh = n >> 7, f = n & 127;
                size_t base = ((size_t)((b << 3) + hh) << 18) + ((size_t)f << 11);
                int jpos = (jj & ~63) | ((((jj >> 3) & 7) ^ (f & 7)) << 3) | (jj & 7);
                unsigned long long pk = 0;
                #pragma unroll
                for (int p = 0; p < 4; p++)
                    pk |= (unsigned long long)f2bf(acc[i][j][p] + bb[j]) << (16 * p);
                *(unsigned long long*)&vhb[base + jpos] = pk;
            }
        }
    }
}

// ---------------------------------------------------------------------------
// final: out = abuf(bf16, f'-permuted cols) @ Wot(perm-baked)^T + bo, fp32 out
// ---------------------------------------------------------------------------
__global__ __launch_bounds__(256) void gemm_out(
    const unsigned short* __restrict__ abuf, const unsigned short* __restrict__ Wot,
    const float* __restrict__ bo, float* __restrict__ out)
{
    __shared__ unsigned short As[128][32];
    __shared__ unsigned short Bs[64][32];
    const int gm0 = blockIdx.y << 7, gn0 = blockIdx.x << 6;

    f32x4 acc[4][2];
    #pragma unroll
    for (int i = 0; i < 4; i++)
        #pragma unroll
        for (int j = 0; j < 2; j++) acc[i][j] = (f32x4){0.f, 0.f, 0.f, 0.f};

    gemm_core<64>(abuf, Wot, 1024, gm0, gn0, As, Bs, acc);

    const int lane = threadIdx.x & 63, w = threadIdx.x >> 6;
    const int wm = (w & 1) << 6, wn = (w >> 1) << 5;
    const int l15 = lane & 15, quad = lane >> 4;
    float bb[2];
    #pragma unroll
    for (int j = 0; j < 2; j++) bb[j] = bo[gn0 + wn + (j << 4) + l15];
    #pragma unroll
    for (int i = 0; i < 4; i++) {
        int mb = gm0 + wm + (i << 4) + (quad << 2);
        #pragma unroll
        for (int p = 0; p < 4; p++)
            #pragma unroll
            for (int j = 0; j < 2; j++)
                out[(size_t)(mb + p) * 1024 + gn0 + wn + (j << 4) + l15] = acc[i][j][p] + bb[j];
    }
}

// ---------------------------------------------------------------------------
// MFMA flash attention. 1024 blocks = (jsplit4, b, qt16, h). j-tile 64.
// Pure gld16 staging (swizzle baked in khb/vhb). S^T softmax (lane owns a
// q-row). Ps: stride 64, 16B-block XOR swizzle -> conflict-free both ways.
// Output: bf16 partials in f'-permuted layout + (m,l).
// ---------------------------------------------------------------------------
__global__ __launch_bounds__(256) void attn_mfma(
    const unsigned short* __restrict__ qbuf, const unsigned short* __restrict__ khb,
    const unsigned short* __restrict__ vhb, const unsigned long long* __restrict__ mpk,
    unsigned short* __restrict__ Opart, float* __restrict__ ml)
{
    __shared__ unsigned short Ks[64 * 64];     // [j][d-chunk swz]
    __shared__ unsigned short VsT[128 * 64];   // [f][j-chunk swz]
    __shared__ unsigned short Ps[64 * 64];     // [q][16B-block swz]

    const int t = threadIdx.x;
    const int bid = blockIdx.x;
    const int hs = bid >> 8, r = bid & 255;
    const int h = r & 7, qt = (r >> 3) & 15, b = r >> 7;
    const int q0 = qt << 6;
    const int lane = t & 63, w = t >> 6, l15 = lane & 15, quad = lane >> 4;
    const int v7 = l15 & 7;

    const unsigned short* qrow = qbuf + (((size_t)(b << 10) + q0 + (w << 4) + l15) << 9) + (h << 6);
    const bf16x8 aq0 = *(const bf16x8*)&qrow[quad << 3];
    const bf16x8 aq1 = *(const bf16x8*)&qrow[32 + (quad << 3)];

    f32x4 acc[8];
    #pragma unroll
    for (int ct = 0; ct < 8; ct++) acc[ct] = (f32x4){0.f, 0.f, 0.f, 0.f};
    float m_l = -3.0e38f, l_l = 0.f;

    const unsigned short* kh = khb + ((size_t)((b << 3) + h) << 17);
    const unsigned short* vh = vhb + ((size_t)((b << 3) + h) << 18);
    const unsigned long long* mrow = mpk + (((size_t)(b << 10) + q0 + (w << 4) + l15) << 5) + (hs << 3);
    const int prow = ((w << 4) + l15) << 6;

    for (int jt = 0; jt < 8; jt++) {
        const int j0 = (hs << 9) + (jt << 6);
        __syncthreads();
        {   // K tile: 8KB contiguous
            const unsigned short* kg = kh + ((size_t)j0 << 6);
            int o = (w << 10) + (lane << 3);
            gld16(kg + o, Ks + o);
            gld16(kg + o + 512, Ks + o + 512);
        }
        #pragma unroll
        for (int it = 0; it < 4; it++) {    // V tile: 128f x 64j
            int f0 = (w << 5) + (it << 3);
            gld16(vh + ((size_t)(f0 + (lane >> 3)) << 11) + j0 + ((lane & 7) << 3),
                  VsT + (f0 << 6) + (lane << 3));
        }
        __syncthreads();

        const unsigned long long mw = mrow[jt];

        // S^T = K Q^T: lane col=q=l15, row j = n*16+quad*4+p
        f32x4 s[4];
        #pragma unroll
        for (int n = 0; n < 4; n++) {
            int rowk = (n << 4) + l15;
            bf16x8 bk0 = *(const bf16x8*)&Ks[(rowk << 6) + ((quad ^ v7) << 3)];
            bf16x8 bk1 = *(const bf16x8*)&Ks[(rowk << 6) + (((quad + 4) ^ v7) << 3)];
            s[n] = (f32x4){0.f, 0.f, 0.f, 0.f};
            s[n] = __builtin_amdgcn_mfma_f32_16x16x32_bf16(bk0, aq0, s[n], 0, 0, 0);
            s[n] = __builtin_amdgcn_mfma_f32_16x16x32_bf16(bk1, aq1, s[n], 0, 0, 0);
        }
        #pragma unroll
        for (int n = 0; n < 4; n++)
            #pragma unroll
            for (int p = 0; p < 4; p++) {
                float sv = s[n][p] * 0.125f;
                s[n][p] = ((mw >> ((n << 4) + (quad << 2) + p)) & 1ull) ? sv : -3.0e38f;
            }

        float mt = s[0][0];
        #pragma unroll
        for (int n = 0; n < 4; n++)
            #pragma unroll
            for (int p = 0; p < 4; p++) mt = fmaxf(mt, s[n][p]);
        mt = fmaxf(mt, __shfl_xor(mt, 16, 64));
        mt = fmaxf(mt, __shfl_xor(mt, 32, 64));
        float mn = fmaxf(m_l, mt);
        float ls = 0.f;
        #pragma unroll
        for (int n = 0; n < 4; n++) {
            float e0 = __expf(s[n][0] - mn), e1 = __expf(s[n][1] - mn);
            float e2 = __expf(s[n][2] - mn), e3 = __expf(s[n][3] - mn);
            ls += (e0 + e1) + (e2 + e3);
            unsigned long long pk = (unsigned long long)f2bf(e0)
                | ((unsigned long long)f2bf(e1) << 16)
                | ((unsigned long long)f2bf(e2) << 32)
                | ((unsigned long long)f2bf(e3) << 48);
            int mblk = ((n << 1) + (quad >> 1)) ^ v7;
            *(unsigned long long*)&Ps[prow + (mblk << 3) + ((quad & 1) << 2)] = pk;
        }
        ls += __shfl_xor(ls, 16, 64);
        ls += __shfl_xor(ls, 32, 64);
        float al = __expf(m_l - mn);
        l_l = l_l * al + ls;
        m_l = mn;

        float ar[4];
        #pragma unroll
        for (int p = 0; p < 4; p++)
            ar[p] = __shfl(al, (lane & 48) | ((quad << 2) + p), 64);
        #pragma unroll
        for (int ct = 0; ct < 8; ct++)
            #pragma unroll
            for (int p = 0; p < 4; p++) acc[ct][p] *= ar[p];

        // O += P V
        bf16x8 ap[2];
        #pragma unroll
        for (int win = 0; win < 2; win++) {
            int mblk = ((win << 2) + quad) ^ v7;
            ap[win] = *(const bf16x8*)&Ps[prow + (mblk << 3)];
        }
        #pragma unroll
        for (int ct = 0; ct < 8; ct++) {
            int f = (ct << 4) + l15;
            #pragma unroll
            for (int win = 0; win < 2; win++) {
                int c = (win << 2) + quad;
                bf16x8 bv = *(const bf16x8*)&VsT[(f << 6) + ((c ^ v7) << 3)];
                acc[ct] = __builtin_amdgcn_mfma_f32_16x16x32_bf16(ap[win], bv, acc[ct], 0, 0, 0);
            }
        }
    }

    #pragma unroll
    for (int p = 0; p < 4; p++) {
        int q = q0 + (w << 4) + (quad << 2) + p;
        size_t idx = ((size_t)hs << 14) + ((size_t)((b << 3) + h) << 10) + q;
        uint4 pk;
        pk.x = (unsigned)f2bf(acc[0][p]) | ((unsigned)f2bf(acc[1][p]) << 16);
        pk.y = (unsigned)f2bf(acc[2][p]) | ((unsigned)f2bf(acc[3][p]) << 16);
        pk.z = (unsigned)f2bf(acc[4][p]) | ((unsigned)f2bf(acc[5][p]) << 16);
        pk.w = (unsigned)f2bf(acc[6][p]) | ((unsigned)f2bf(acc[7][p]) << 16);
        *(uint4*)&Opart[(idx << 7) + (l15 << 3)] = pk;
    }
    if (quad == 0) {
        int q = q0 + (w << 4) + l15;
        size_t idx = ((size_t)hs << 14) + ((size_t)((b << 3) + h) << 10) + q;
        ml[(idx << 1) + 0] = m_l;
        ml[(idx << 1) + 1] = l_l;
    }
}

// ---------------------------------------------------------------------------
// Combine 4 j-split partials -> abuf bf16 (f'-permuted cols)
// ---------------------------------------------------------------------------
__global__ __launch_bounds__(256) void attn_combine(
    const unsigned short* __restrict__ Opart, const float* __restrict__ ml,
    unsigned short* __restrict__ abuf)
{
    int id = (blockIdx.x << 8) + threadIdx.x;          // 524288
    int bhq = id >> 5, c = id & 31;
    float2 m0 = ((const float2*)ml)[bhq];
    float2 m1 = ((const float2*)ml)[16384 + bhq];
    float2 m2 = ((const float2*)ml)[32768 + bhq];
    float2 m3 = ((const float2*)ml)[49152 + bhq];
    float M = fmaxf(fmaxf(m0.x, m1.x), fmaxf(m2.x, m3.x));
    float a0 = __expf(m0.x - M), a1 = __expf(m1.x - M);
    float a2 = __expf(m2.x - M), a3 = __expf(m3.x - M);
    float inv = 1.0f / (m0.y * a0 + m1.y * a1 + m2.y * a2 + m3.y * a3);
    a0 *= inv; a1 *= inv; a2 *= inv; a3 *= inv;
    float o[4] = {0.f, 0.f, 0.f, 0.f};
    float as[4] = {a0, a1, a2, a3};
    #pragma unroll
    for (int s = 0; s < 4; s++) {
        uint2 v = *(const uint2*)&Opart[((size_t)(s * 16384 + bhq) << 7) + (c << 2)];
        o[0] += as[s] * bf2f((unsigned short)(v.x & 0xFFFF));
        o[1] += as[s] * bf2f((unsigned short)(v.x >> 16));
        o[2] += as[s] * bf2f((unsigned short)(v.y & 0xFFFF));
        o[3] += as[s] * bf2f((unsigned short)(v.y >> 16));
    }
    int b = bhq >> 13, hh = (bhq >> 10) & 7, q = bhq & 1023;
    unsigned long long pk = (unsigned long long)f2bf(o[0])
        | ((unsigned long long)f2bf(o[1]) << 16)
        | ((unsigned long long)f2bf(o[2]) << 32)
        | ((unsigned long long)f2bf(o[3]) << 48);
    *(unsigned long long*)&abuf[((size_t)((b << 10) + q) << 10) + (hh << 7) + (c << 2)] = pk;
}

// ---------------------------------------------------------------------------
extern "C" void kernel_launch(void* const* d_in, const int* in_sizes, int n_in,
                              void* d_out, int out_size, void* d_ws, size_t ws_size,
                              hipStream_t stream)
{
    const float* x        = (const float*)d_in[0];
    const float* context  = (const float*)d_in[1];
    const float* context2 = (const float*)d_in[2];
    const int*   mask1    = (const int*)d_in[3];
    const int*   mask2    = (const int*)d_in[4];
    const float* Wq  = (const float*)d_in[5];
    const float* bq  = (const float*)d_in[6];
    const float* Wk1 = (const float*)d_in[7];
    const float* bk1 = (const float*)d_in[8];
    const float* Wv1 = (const float*)d_in[9];
    const float* bv1 = (const float*)d_in[10];
    const float* Wk2 = (const float*)d_in[11];
    const float* bk2 = (const float*)d_in[12];
    const float* Wv2 = (const float*)d_in[13];
    const float* bv2 = (const float*)d_in[14];
    const float* Wo  = (const float*)d_in[15];
    const float* bo  = (const float*)d_in[16];
    float* out = (float*)d_out;

    // Workspace (MB): Wot[0,2) xb[2,6) c1b[6,10) c2b[10,14) Wqt[14,15)
    // Wk1t[15,16) Wk2t[16,17) Wv1t[17,19) Wv2t[19,21) qbuf[21,23) khb[23,27)
    // vhb[27,35) mpk[35,35.5) mlb[35.5,36).
    // Post-proj overlap: Opart[2,18) (xb..Wv1t dead), abuf[19,23) (Wv2t dead,
    // qbuf dead before combine writes).
    char* W = (char*)d_ws;
    unsigned short* Wot  = (unsigned short*)(W);
    unsigned short* xb   = (unsigned short*)(W + (2ull  << 20));
    unsigned short* c1b  = (unsigned short*)(W + (6ull  << 20));
    unsigned short* c2b  = (unsigned short*)(W + (10ull << 20));
    unsigned short* Wqt  = (unsigned short*)(W + (14ull << 20));
    unsigned short* Wk1t = (unsigned short*)(W + (15ull << 20));
    unsigned short* Wk2t = (unsigned short*)(W + (16ull << 20));
    unsigned short* Wv1t = (unsigned short*)(W + (17ull << 20));
    unsigned short* Wv2t = (unsigned short*)(W + (19ull << 20));
    unsigned short* qbuf = (unsigned short*)(W + (21ull << 20));
    unsigned short* khb  = (unsigned short*)(W + (23ull << 20));
    unsigned short* vhb  = (unsigned short*)(W + (27ull << 20));
    unsigned long long* mpk = (unsigned long long*)(W + (35ull << 20));
    float*          mlb  = (float*)(W + (35ull << 20) + (1ull << 19));
    unsigned short* Opart = (unsigned short*)(W + (2ull << 20));
    unsigned short* abuf  = (unsigned short*)(W + (19ull << 20));

    prep<<<dim3(4736), 256, 0, stream>>>(x, context, context2, mask1, mask2,
                                         Wq, Wk1, Wk2, Wv1, Wv2, Wo,
                                         xb, c1b, c2b, Wqt, Wk1t, Wk2t, Wv1t, Wv2t, Wot, mpk);
    proj_all<<<dim3(448), 256, 0, stream>>>(xb, c1b, c2b, Wqt, Wk1t, Wk2t, Wv1t, Wv2t,
                                            bq, bk1, bk2, bv1, bv2, qbuf, khb, vhb);
    attn_mfma<<<dim3(1024), 256, 0, stream>>>(qbuf, khb, vhb, mpk, Opart, mlb);
    attn_combine<<<dim3(2048), 256, 0, stream>>>(Opart, mlb, abuf);
    gemm_out<<<dim3(16, 16), 256, 0, stream>>>(abuf, Wot, bo, out);
}